// Round 2
// baseline (8832.969 us; speedup 1.0000x reference)
//
#include <hip/hip_runtime.h>
#include <hip/hip_bf16.h>

#define NN 100000
#define EE 500000
#define H 8
#define D 32
#define INF_ 32
#define HD 256
#define SLOPE 0.2f

typedef unsigned short u16;
typedef unsigned int u32;

__device__ __forceinline__ float leaky(float x) { return x >= 0.f ? x : SLOPE * x; }
// monotonic float->uint encoding for atomicMax
__device__ __forceinline__ u32 encf(float x) {
    u32 u = __float_as_uint(x);
    return (u & 0x80000000u) ? ~u : (u | 0x80000000u);
}
__device__ __forceinline__ float decf(u32 v) {
    return (v & 0x80000000u) ? __uint_as_float(v ^ 0x80000000u) : __uint_as_float(~v);
}
__device__ __forceinline__ u16 bf16r(float x) {  // round-to-nearest-even bf16
    u32 u = __float_as_uint(x);
    u += 0x7fffu + ((u >> 16) & 1u);
    return (u16)(u >> 16);
}
__device__ __forceinline__ float bf16f(u16 v) { return __uint_as_float((u32)v << 16); }

// ---------------- tiny prep: ra[4][512] and rel_out[4][256] ----------------
__global__ void k_prep(const float* __restrict__ rel_emb, const float* __restrict__ W_rel,
                       const float* __restrict__ W_prop, const float* __restrict__ b_prop,
                       float* __restrict__ ra, float* __restrict__ rel_out) {
    int idx = blockIdx.x * blockDim.x + threadIdx.x;
    if (idx < 4 * 512) {
        int r = idx >> 9, o = idx & 511;
        float s = 0.f;
        #pragma unroll
        for (int i = 0; i < INF_; ++i) s += rel_emb[r * INF_ + i] * W_rel[(r * INF_ + i) * 512 + o];
        ra[idx] = s;
    } else if (idx < 4 * 512 + 4 * 256) {
        int j = idx - 2048;
        int r = j >> 8;
        float s = b_prop[j];
        #pragma unroll
        for (int i = 0; i < INF_; ++i) s += rel_emb[r * INF_ + i] * W_prop[(r * INF_ + i) * 256 + (j & 255)];
        rel_out[j] = s;
    }
}

// ---------------- projections P[q] = feat[REV[q]] @ W_node[st[q]], + scores ----------------
// P[q] is fs for relation q and fd for relation REV[q].
__global__ __launch_bounds__(256) void k_proj(const float* __restrict__ feat,
                                              const float* __restrict__ W_node,
                                              const float* __restrict__ ra_g,
                                              float* __restrict__ e_src, float* __restrict__ e_dst,
                                              u16* __restrict__ P) {
    const int q = blockIdx.y;
    const int REVt[4] = {1, 0, 3, 2};
    const int widxt[4] = {0, 1, 0, 1};
    const int fidx = REVt[q], widx = widxt[q], rq = REVt[q];
    __shared__ float wl[INF_ * H * 33];   // [i][h][j] padded
    __shared__ float fl[32 * 33];         // 32 node rows
    __shared__ float ras[H * D], rad[H * D];
    const int t = threadIdx.x;
    const int node0 = blockIdx.x * 32;

    const float* W = W_node + (size_t)widx * INF_ * HD;
    #pragma unroll
    for (int k = 0; k < 32; ++k)  // i=k, c=t
        wl[(k * 8 + (t >> 5)) * 33 + (t & 31)] = W[k * 256 + t];
    const float* F = feat + (size_t)fidx * NN * INF_ + (size_t)node0 * INF_;
    #pragma unroll
    for (int k = 0; k < 4; ++k) {
        int idx = k * 256 + t;
        fl[(idx >> 5) * 33 + (idx & 31)] = F[idx];
    }
    {
        int h = t >> 5, j = t & 31;
        ras[t] = ra_g[q * 512 + h * 64 + 32 + j];
        rad[t] = ra_g[rq * 512 + h * 64 + j];
    }
    __syncthreads();

    const int h = t & 7, nl = t >> 3;
    const int n = node0 + nl;
    float acc[D];
    #pragma unroll
    for (int j = 0; j < D; ++j) acc[j] = 0.f;
    #pragma unroll
    for (int i = 0; i < INF_; ++i) {
        float f = fl[nl * 33 + i];
        const float* w = &wl[(i * 8 + h) * 33];
        #pragma unroll
        for (int j = 0; j < D; ++j) acc[j] = fmaf(f, w[j], acc[j]);
    }
    float es = 0.f, ed = 0.f;
    #pragma unroll
    for (int j = 0; j < D; ++j) { es += acc[j] * ras[h * 32 + j]; ed += acc[j] * rad[h * 32 + j]; }
    e_src[((size_t)q * NN + n) * H + h] = es;
    e_dst[((size_t)rq * NN + n) * H + h] = ed;

    u16 pk[32];
    #pragma unroll
    for (int j = 0; j < D; ++j) pk[j] = bf16r(acc[j]);
    uint4* dst4 = (uint4*)(P + ((size_t)q * NN + n) * HD + h * D);
    const uint4* s4 = (const uint4*)pk;
    dst4[0] = s4[0]; dst4[1] = s4[1]; dst4[2] = s4[2]; dst4[3] = s4[3];
}

// ---------------- edge pass 1: segment max ----------------
__global__ void k_edge_max(const int* __restrict__ src, const int* __restrict__ dst,
                           const float* __restrict__ e_src, const float* __restrict__ e_dst,
                           u32* __restrict__ m) {
    int idx = blockIdx.x * blockDim.x + threadIdx.x;
    if (idx >= 4 * EE) return;
    int r = idx / EE, e = idx - r * EE;
    int s = src[(size_t)r * EE + e], d = dst[(size_t)r * EE + e];
    const float4* es4 = (const float4*)(e_src + ((size_t)r * NN + s) * H);
    const float4* ed4 = (const float4*)(e_dst + ((size_t)r * NN + d) * H);
    float4 a0 = es4[0], a1 = es4[1], b0 = ed4[0], b1 = ed4[1];
    u32* mp = m + ((size_t)r * NN + d) * H;
    atomicMax(&mp[0], encf(leaky(a0.x + b0.x)));
    atomicMax(&mp[1], encf(leaky(a0.y + b0.y)));
    atomicMax(&mp[2], encf(leaky(a0.z + b0.z)));
    atomicMax(&mp[3], encf(leaky(a0.w + b0.w)));
    atomicMax(&mp[4], encf(leaky(a1.x + b1.x)));
    atomicMax(&mp[5], encf(leaky(a1.y + b1.y)));
    atomicMax(&mp[6], encf(leaky(a1.z + b1.z)));
    atomicMax(&mp[7], encf(leaky(a1.w + b1.w)));
}

// ---------------- edge pass 2: exp-sum ----------------
__global__ void k_edge_exp(const int* __restrict__ src, const int* __restrict__ dst,
                           const float* __restrict__ e_src, const float* __restrict__ e_dst,
                           const u32* __restrict__ m, float* __restrict__ z) {
    int idx = blockIdx.x * blockDim.x + threadIdx.x;
    if (idx >= 4 * EE) return;
    int r = idx / EE, e = idx - r * EE;
    int s = src[(size_t)r * EE + e], d = dst[(size_t)r * EE + e];
    const float4* es4 = (const float4*)(e_src + ((size_t)r * NN + s) * H);
    const float4* ed4 = (const float4*)(e_dst + ((size_t)r * NN + d) * H);
    const uint4* m4 = (const uint4*)(m + ((size_t)r * NN + d) * H);
    float4 a0 = es4[0], a1 = es4[1], b0 = ed4[0], b1 = ed4[1];
    uint4 m0 = m4[0], m1 = m4[1];
    float* zp = z + ((size_t)r * NN + d) * H;
    atomicAdd(&zp[0], __expf(leaky(a0.x + b0.x) - decf(m0.x)));
    atomicAdd(&zp[1], __expf(leaky(a0.y + b0.y) - decf(m0.y)));
    atomicAdd(&zp[2], __expf(leaky(a0.z + b0.z) - decf(m0.z)));
    atomicAdd(&zp[3], __expf(leaky(a0.w + b0.w) - decf(m0.w)));
    atomicAdd(&zp[4], __expf(leaky(a1.x + b1.x) - decf(m1.x)));
    atomicAdd(&zp[5], __expf(leaky(a1.y + b1.y) - decf(m1.y)));
    atomicAdd(&zp[6], __expf(leaky(a1.z + b1.z) - decf(m1.z)));
    atomicAdd(&zp[7], __expf(leaky(a1.w + b1.w) - decf(m1.w)));
}

// ---------------- edge pass 3: normalize + message scatter (one wave per edge) ----------------
__global__ __launch_bounds__(256) void k_edge_msg(const int* __restrict__ src, const int* __restrict__ dst,
                                                  const float* __restrict__ e_src, const float* __restrict__ e_dst,
                                                  const u32* __restrict__ m, const float* __restrict__ z,
                                                  const u16* __restrict__ P, float* agg, int r) {
    int lane = threadIdx.x & 63;
    int e = blockIdx.x * 4 + (threadIdx.x >> 6);
    if (e >= EE) return;
    int s = src[e], d = dst[e];  // src/dst pre-offset by relation on host
    int h = lane >> 3;
    size_t sb = ((size_t)r * NN + s) * H + h, db = ((size_t)r * NN + d) * H + h;
    float a = __expf(leaky(e_src[sb] + e_dst[db]) - decf(m[db])) / z[db];
    ushort4 f4 = *(const ushort4*)(P + ((size_t)r * NN + s) * HD + lane * 4);
    float* ap = agg + (size_t)d * HD + lane * 4;
    atomicAdd(&ap[0], bf16f(f4.x) * a);
    atomicAdd(&ap[1], bf16f(f4.y) * a);
    atomicAdd(&ap[2], bf16f(f4.z) * a);
    atomicAdd(&ap[3], bf16f(f4.w) * a);
}

// ---------------- finalize: relu, gate+residual, relation crossing ----------------
// aggA/outp may alias (in-place): each thread reads its own chunk before writing it.
__global__ __launch_bounds__(256) void k_final(const float* __restrict__ fA, const float* __restrict__ fB,
                                               const float* __restrict__ Wres, const float* __restrict__ bres,
                                               const float* __restrict__ alpha_t, const float* __restrict__ wx,
                                               const float* aggA, const float* aggB, float* outp) {
    __shared__ float wl[INF_ * H * 33];
    __shared__ float f1[32 * 33], f2[32 * 33];
    __shared__ float wxs[256], brs[256];
    const int t = threadIdx.x;
    const int node0 = blockIdx.x * 32;
    #pragma unroll
    for (int k = 0; k < 32; ++k)
        wl[(k * 8 + (t >> 5)) * 33 + (t & 31)] = Wres[k * 256 + t];
    #pragma unroll
    for (int k = 0; k < 4; ++k) {
        int idx = k * 256 + t;
        f1[(idx >> 5) * 33 + (idx & 31)] = fA[(size_t)node0 * INF_ + idx];
        f2[(idx >> 5) * 33 + (idx & 31)] = fB[(size_t)node0 * INF_ + idx];
    }
    wxs[t] = wx[t];
    brs[t] = bres[t];
    __syncthreads();

    const int h = t & 7, nl = t >> 3;
    const int n = node0 + nl;
    const float g = 1.f / (1.f + __expf(-alpha_t[0]));
    float r1a[D], r2a[D];
    #pragma unroll
    for (int j = 0; j < D; ++j) { r1a[j] = 0.f; r2a[j] = 0.f; }
    #pragma unroll
    for (int i = 0; i < INF_; ++i) {
        float fa = f1[nl * 33 + i], fb = f2[nl * 33 + i];
        const float* w = &wl[(i * 8 + h) * 33];
        #pragma unroll
        for (int j = 0; j < D; ++j) { r1a[j] = fmaf(fa, w[j], r1a[j]); r2a[j] = fmaf(fb, w[j], r2a[j]); }
    }
    const float* A1 = aggA + (size_t)n * HD + h * D;
    const float* A2 = aggB + (size_t)n * HD + h * D;
    float at1 = 0.f, at2 = 0.f;
    #pragma unroll
    for (int j = 0; j < D; ++j) {
        float o1 = fmaxf(A1[j], 0.f) * g + (r1a[j] + brs[h * 32 + j]) * (1.f - g);
        float o2 = fmaxf(A2[j], 0.f) * g + (r2a[j] + brs[h * 32 + j]) * (1.f - g);
        r1a[j] = o1; r2a[j] = o2;
        at1 += o1 * wxs[h * 32 + j];
        at2 += o2 * wxs[h * 32 + j];
    }
    at1 = leaky(at1); at2 = leaky(at2);
    float mx = fmaxf(at1, at2);
    float e1 = __expf(at1 - mx), e2 = __expf(at2 - mx);
    float inv = 1.f / (e1 + e2);
    float w1 = e1 * inv, w2 = e2 * inv;
    float* op = outp + (size_t)n * HD + h * D;
    #pragma unroll
    for (int j = 0; j < D; ++j) op[j] = r1a[j] * w1 + r2a[j] * w2;
}

extern "C" void kernel_launch(void* const* d_in, const int* in_sizes, int n_in,
                              void* d_out, int out_size, void* d_ws, size_t ws_size,
                              hipStream_t stream) {
    const float* feat    = (const float*)d_in[0];
    const float* rel_emb = (const float*)d_in[1];
    const float* W_node  = (const float*)d_in[2];
    const float* W_rel   = (const float*)d_in[3];
    const float* W_prop  = (const float*)d_in[4];
    const float* b_prop  = (const float*)d_in[5];
    const float* W_res   = (const float*)d_in[6];
    const float* b_res   = (const float*)d_in[7];
    const float* alpha   = (const float*)d_in[8];
    const float* Wx      = (const float*)d_in[9];
    const int*   src     = (const int*)d_in[10];
    const int*   dst     = (const int*)d_in[11];
    float* out = (float*)d_out;

    // ws layout: ra | e_src | e_dst | P(bf16) | m | z | agg_ws(agg3,agg2)
    char* ws = (char*)d_ws;
    float* ra    = (float*)ws;                          // 8 KB
    float* e_src = (float*)(ws + 8192);                 // 12.8 MB
    float* e_dst = e_src + (size_t)4 * NN * H;          // 12.8 MB
    u16*   P     = (u16*)(e_dst + (size_t)4 * NN * H);  // 204.8 MB
    u32*   m     = (u32*)((char*)P + (size_t)4 * NN * HD * 2);
    float* z     = (float*)(m + (size_t)4 * NN * H);
    float* agg_ws = z + (size_t)4 * NN * H;             // 204.8 MB
    // agg[1] -> d_out node_out[0] region, agg[0] -> node_out[1] region (in-place finalize)
    float* agg1 = out;
    float* agg0 = out + (size_t)NN * HD;
    float* agg3 = agg_ws;
    float* agg2 = agg_ws + (size_t)NN * HD;
    float* aggs[4] = {agg0, agg1, agg2, agg3};

    // zero: d_out node regions (accumulators) + m,z,agg_ws (contiguous)
    hipMemsetAsync(out, 0, (size_t)2 * NN * HD * 4, stream);
    hipMemsetAsync(m, 0, (size_t)4 * NN * H * 4 * 2 + (size_t)2 * NN * HD * 4, stream);

    k_prep<<<12, 256, 0, stream>>>(rel_emb, W_rel, W_prop, b_prop, ra, out + (size_t)2 * NN * HD);
    k_proj<<<dim3(NN / 32, 4), 256, 0, stream>>>(feat, W_node, ra, e_src, e_dst, P);
    int eb = (4 * EE + 255) / 256;
    k_edge_max<<<eb, 256, 0, stream>>>(src, dst, e_src, e_dst, m);
    k_edge_exp<<<eb, 256, 0, stream>>>(src, dst, e_src, e_dst, m, z);
    for (int r = 0; r < 4; ++r)
        k_edge_msg<<<EE / 4, 256, 0, stream>>>(src + (size_t)r * EE, dst + (size_t)r * EE,
                                               e_src, e_dst, m, z, P, aggs[r], r);
    // type 0 (A): outs[1], outs[3]; type 1 (B): outs[0], outs[2]
    k_final<<<NN / 32, 256, 0, stream>>>(feat + (size_t)1 * NN * INF_, feat + (size_t)3 * NN * INF_,
                                         W_res, b_res, alpha + 0, Wx,
                                         agg1, agg3, out);
    k_final<<<NN / 32, 256, 0, stream>>>(feat + (size_t)0 * NN * INF_, feat + (size_t)2 * NN * INF_,
                                         W_res + (size_t)INF_ * HD, b_res + 256, alpha + 1, Wx + 256,
                                         agg0, agg2, out + (size_t)NN * HD);
}

// Round 3
// 1421.582 us; speedup vs baseline: 6.2135x; 6.2135x over previous
//
#include <hip/hip_runtime.h>
#include <hip/hip_bf16.h>

#define NN 100000
#define EE 500000
#define H 8
#define D 32
#define INF_ 32
#define HD 256
#define SLOPE 0.2f
#define L_ (4 * NN)          // 400000 flattened (rel,node) slots
#define NB_ ((L_ + 255) / 256)  // 1563 scan blocks

typedef unsigned short u16;
typedef unsigned int u32;

__device__ __forceinline__ float leaky(float x) { return x >= 0.f ? x : SLOPE * x; }
__device__ __forceinline__ u16 bf16r(float x) {
    u32 u = __float_as_uint(x);
    u += 0x7fffu + ((u >> 16) & 1u);
    return (u16)(u >> 16);
}
__device__ __forceinline__ float bf16f(u16 v) { return __uint_as_float((u32)v << 16); }

// ---------------- tiny prep: ra[4][512] and rel_out[4][256] ----------------
__global__ void k_prep(const float* __restrict__ rel_emb, const float* __restrict__ W_rel,
                       const float* __restrict__ W_prop, const float* __restrict__ b_prop,
                       float* __restrict__ ra, float* __restrict__ rel_out) {
    int idx = blockIdx.x * blockDim.x + threadIdx.x;
    if (idx < 4 * 512) {
        int r = idx >> 9, o = idx & 511;
        float s = 0.f;
        #pragma unroll
        for (int i = 0; i < INF_; ++i) s += rel_emb[r * INF_ + i] * W_rel[(r * INF_ + i) * 512 + o];
        ra[idx] = s;
    } else if (idx < 4 * 512 + 4 * 256) {
        int j = idx - 2048;
        int r = j >> 8;
        float s = b_prop[j];
        #pragma unroll
        for (int i = 0; i < INF_; ++i) s += rel_emb[r * INF_ + i] * W_prop[(r * INF_ + i) * 256 + (j & 255)];
        rel_out[j] = s;
    }
}

// ---------------- projections P[q] = feat[REV[q]] @ W_node[st[q]], + scores ----------------
__global__ __launch_bounds__(256) void k_proj(const float* __restrict__ feat,
                                              const float* __restrict__ W_node,
                                              const float* __restrict__ ra_g,
                                              float* __restrict__ e_src, float* __restrict__ e_dst,
                                              u16* __restrict__ P) {
    const int q = blockIdx.y;
    const int REVt[4] = {1, 0, 3, 2};
    const int widxt[4] = {0, 1, 0, 1};
    const int fidx = REVt[q], widx = widxt[q], rq = REVt[q];
    __shared__ float wl[INF_ * H * 33];
    __shared__ float fl[32 * 33];
    __shared__ float ras[H * D], rad[H * D];
    const int t = threadIdx.x;
    const int node0 = blockIdx.x * 32;

    const float* W = W_node + (size_t)widx * INF_ * HD;
    #pragma unroll
    for (int k = 0; k < 32; ++k)
        wl[(k * 8 + (t >> 5)) * 33 + (t & 31)] = W[k * 256 + t];
    const float* F = feat + (size_t)fidx * NN * INF_ + (size_t)node0 * INF_;
    #pragma unroll
    for (int k = 0; k < 4; ++k) {
        int idx = k * 256 + t;
        fl[(idx >> 5) * 33 + (idx & 31)] = F[idx];
    }
    {
        int h = t >> 5, j = t & 31;
        ras[t] = ra_g[q * 512 + h * 64 + 32 + j];
        rad[t] = ra_g[rq * 512 + h * 64 + j];
    }
    __syncthreads();

    const int h = t & 7, nl = t >> 3;
    const int n = node0 + nl;
    float acc[D];
    #pragma unroll
    for (int j = 0; j < D; ++j) acc[j] = 0.f;
    #pragma unroll
    for (int i = 0; i < INF_; ++i) {
        float f = fl[nl * 33 + i];
        const float* w = &wl[(i * 8 + h) * 33];
        #pragma unroll
        for (int j = 0; j < D; ++j) acc[j] = fmaf(f, w[j], acc[j]);
    }
    float es = 0.f, ed = 0.f;
    #pragma unroll
    for (int j = 0; j < D; ++j) { es += acc[j] * ras[h * 32 + j]; ed += acc[j] * rad[h * 32 + j]; }
    e_src[((size_t)q * NN + n) * H + h] = es;
    e_dst[((size_t)rq * NN + n) * H + h] = ed;

    u16 pk[32];
    #pragma unroll
    for (int j = 0; j < D; ++j) pk[j] = bf16r(acc[j]);
    uint4* dst4 = (uint4*)(P + ((size_t)q * NN + n) * HD + h * D);
    const uint4* s4 = (const uint4*)pk;
    dst4[0] = s4[0]; dst4[1] = s4[1]; dst4[2] = s4[2]; dst4[3] = s4[3];
}

// ---------------- CSR build ----------------
__global__ void k_count(const int* __restrict__ dst, u32* __restrict__ deg) {
    int idx = blockIdx.x * blockDim.x + threadIdx.x;
    if (idx >= 4 * EE) return;
    int r = idx / EE;
    atomicAdd(&deg[r * NN + dst[idx]], 1u);
}

__global__ void k_scan1(const u32* __restrict__ deg, u32* __restrict__ incl, u32* __restrict__ bsum) {
    __shared__ u32 sm[256];
    const int t = threadIdx.x;
    int i = blockIdx.x * 256 + t;
    u32 v = (i < L_) ? deg[i] : 0u;
    sm[t] = v;
    __syncthreads();
    for (int ofs = 1; ofs < 256; ofs <<= 1) {
        u32 x = (t >= ofs) ? sm[t - ofs] : 0u;
        __syncthreads();
        sm[t] += x;
        __syncthreads();
    }
    if (i < L_) incl[i] = sm[t];
    if (t == 255) bsum[blockIdx.x] = sm[255];
}

__global__ void k_scan2(const u32* __restrict__ bsum, u32* __restrict__ bofs) {
    __shared__ u32 sm[256];
    __shared__ u32 runS;
    const int t = threadIdx.x;
    if (t == 0) runS = 0u;
    __syncthreads();
    for (int c = 0; c < NB_; c += 256) {
        u32 v = (c + t < NB_) ? bsum[c + t] : 0u;
        sm[t] = v;
        __syncthreads();
        for (int ofs = 1; ofs < 256; ofs <<= 1) {
            u32 x = (t >= ofs) ? sm[t - ofs] : 0u;
            __syncthreads();
            sm[t] += x;
            __syncthreads();
        }
        u32 excl = sm[t] - v;
        if (c + t < NB_) bofs[c + t] = runS + excl;
        __syncthreads();
        if (t == 255) runS += sm[255];
        __syncthreads();
    }
}

__global__ void k_scan3(const u32* __restrict__ deg, const u32* __restrict__ incl,
                        const u32* __restrict__ bofs, u32* __restrict__ offsets,
                        u32* __restrict__ cursor) {
    int i = blockIdx.x * 256 + threadIdx.x;
    if (i >= L_) return;
    u32 excl = incl[i] - deg[i] + bofs[i >> 8];
    offsets[i] = excl;
    cursor[i] = excl;
}

__global__ void k_fill(const int* __restrict__ src, const int* __restrict__ dst,
                       u32* __restrict__ cursor, int* __restrict__ esorted) {
    int idx = blockIdx.x * blockDim.x + threadIdx.x;
    if (idx >= 4 * EE) return;
    int r = idx / EE;
    u32 pos = atomicAdd(&cursor[r * NN + dst[idx]], 1u);
    esorted[pos] = src[idx];
}

// ---------------- per-dst-node fused softmax + message aggregation ----------------
// one wave per dst node; lanes own 4 feature elems; no atomics.
__global__ __launch_bounds__(256) void k_node_msg(const u32* __restrict__ offsets,
                                                  const u32* __restrict__ deg,
                                                  const int* __restrict__ esorted,
                                                  const float* __restrict__ e_src,
                                                  const float* __restrict__ e_dst,
                                                  const u16* __restrict__ P,
                                                  float* __restrict__ agg, int r) {
    const int t = threadIdx.x;
    const int lane = t & 63;
    const int n = blockIdx.x * 4 + (t >> 6);
    const int h = lane >> 3;
    const int i = r * NN + n;
    const u32 off = offsets[i];
    const u32 dg = deg[i];
    float* ap = agg + (size_t)n * HD + lane * 4;
    if (dg == 0) {
        *(float4*)ap = make_float4(0.f, 0.f, 0.f, 0.f);
        return;
    }
    const float ed = e_dst[(size_t)i * H + h];
    const float* esr = e_src + (size_t)r * NN * H;
    float mmax = -1e30f;
    for (u32 k = 0; k < dg; ++k) {
        int s = esorted[off + k];
        float sc = leaky(esr[(size_t)s * H + h] + ed);
        mmax = fmaxf(mmax, sc);
    }
    float z = 0.f, a0 = 0.f, a1 = 0.f, a2 = 0.f, a3 = 0.f;
    const u16* Pr = P + (size_t)r * NN * HD;
    for (u32 k = 0; k < dg; ++k) {
        int s = esorted[off + k];
        float sc = leaky(esr[(size_t)s * H + h] + ed);
        float a = __expf(sc - mmax);
        z += a;
        ushort4 f4 = *(const ushort4*)(Pr + (size_t)s * HD + lane * 4);
        a0 = fmaf(bf16f(f4.x), a, a0);
        a1 = fmaf(bf16f(f4.y), a, a1);
        a2 = fmaf(bf16f(f4.z), a, a2);
        a3 = fmaf(bf16f(f4.w), a, a3);
    }
    float inv = 1.f / z;
    *(float4*)ap = make_float4(a0 * inv, a1 * inv, a2 * inv, a3 * inv);
}

// ---------------- finalize: relu, gate+residual, relation crossing ----------------
// aggA/outp may alias (in-place): each thread reads its own chunk before writing it.
__global__ __launch_bounds__(256) void k_final(const float* __restrict__ fA, const float* __restrict__ fB,
                                               const float* __restrict__ Wres, const float* __restrict__ bres,
                                               const float* __restrict__ alpha_t, const float* __restrict__ wx,
                                               const float* aggA, const float* aggB, float* outp) {
    __shared__ float wl[INF_ * H * 33];
    __shared__ float f1[32 * 33], f2[32 * 33];
    __shared__ float wxs[256], brs[256];
    const int t = threadIdx.x;
    const int node0 = blockIdx.x * 32;
    #pragma unroll
    for (int k = 0; k < 32; ++k)
        wl[(k * 8 + (t >> 5)) * 33 + (t & 31)] = Wres[k * 256 + t];
    #pragma unroll
    for (int k = 0; k < 4; ++k) {
        int idx = k * 256 + t;
        f1[(idx >> 5) * 33 + (idx & 31)] = fA[(size_t)node0 * INF_ + idx];
        f2[(idx >> 5) * 33 + (idx & 31)] = fB[(size_t)node0 * INF_ + idx];
    }
    wxs[t] = wx[t];
    brs[t] = bres[t];
    __syncthreads();

    const int h = t & 7, nl = t >> 3;
    const int n = node0 + nl;
    const float g = 1.f / (1.f + __expf(-alpha_t[0]));
    float r1a[D], r2a[D];
    #pragma unroll
    for (int j = 0; j < D; ++j) { r1a[j] = 0.f; r2a[j] = 0.f; }
    #pragma unroll
    for (int i = 0; i < INF_; ++i) {
        float fa = f1[nl * 33 + i], fb = f2[nl * 33 + i];
        const float* w = &wl[(i * 8 + h) * 33];
        #pragma unroll
        for (int j = 0; j < D; ++j) { r1a[j] = fmaf(fa, w[j], r1a[j]); r2a[j] = fmaf(fb, w[j], r2a[j]); }
    }
    const float* A1 = aggA + (size_t)n * HD + h * D;
    const float* A2 = aggB + (size_t)n * HD + h * D;
    float at1 = 0.f, at2 = 0.f;
    #pragma unroll
    for (int j = 0; j < D; ++j) {
        float o1 = fmaxf(A1[j], 0.f) * g + (r1a[j] + brs[h * 32 + j]) * (1.f - g);
        float o2 = fmaxf(A2[j], 0.f) * g + (r2a[j] + brs[h * 32 + j]) * (1.f - g);
        r1a[j] = o1; r2a[j] = o2;
        at1 += o1 * wxs[h * 32 + j];
        at2 += o2 * wxs[h * 32 + j];
    }
    at1 = leaky(at1); at2 = leaky(at2);
    float mx = fmaxf(at1, at2);
    float e1 = __expf(at1 - mx), e2 = __expf(at2 - mx);
    float inv = 1.f / (e1 + e2);
    float w1 = e1 * inv, w2 = e2 * inv;
    float* op = outp + (size_t)n * HD + h * D;
    #pragma unroll
    for (int j = 0; j < D; ++j) op[j] = r1a[j] * w1 + r2a[j] * w2;
}

extern "C" void kernel_launch(void* const* d_in, const int* in_sizes, int n_in,
                              void* d_out, int out_size, void* d_ws, size_t ws_size,
                              hipStream_t stream) {
    const float* feat    = (const float*)d_in[0];
    const float* rel_emb = (const float*)d_in[1];
    const float* W_node  = (const float*)d_in[2];
    const float* W_rel   = (const float*)d_in[3];
    const float* W_prop  = (const float*)d_in[4];
    const float* b_prop  = (const float*)d_in[5];
    const float* W_res   = (const float*)d_in[6];
    const float* b_res   = (const float*)d_in[7];
    const float* alpha   = (const float*)d_in[8];
    const float* Wx      = (const float*)d_in[9];
    const int*   src     = (const int*)d_in[10];
    const int*   dst     = (const int*)d_in[11];
    float* out = (float*)d_out;

    // ws layout: ra | e_src | e_dst | P | deg | offsets | cursor | incl | bsum | bofs | esorted | agg_ws
    char* ws = (char*)d_ws;
    float* ra    = (float*)ws;                            // 8 KB
    float* e_src = (float*)(ws + 8192);                   // 12.8 MB
    float* e_dst = e_src + (size_t)4 * NN * H;            // 12.8 MB
    u16*   P     = (u16*)(e_dst + (size_t)4 * NN * H);    // 204.8 MB
    u32*   deg     = (u32*)((char*)P + (size_t)4 * NN * HD * 2);
    u32*   offsets = deg + L_;
    u32*   cursor  = offsets + L_;
    u32*   incl    = cursor + L_;
    u32*   bsum    = incl + L_;
    u32*   bofs    = bsum + 2048;
    int*   esorted = (int*)(bofs + 2048);                 // 8 MB
    float* agg_ws  = (float*)(esorted + (size_t)4 * EE);  // 204.8 MB
    float* agg1 = out;                                    // in-place finalize targets
    float* agg0 = out + (size_t)NN * HD;
    float* agg3 = agg_ws;
    float* agg2 = agg_ws + (size_t)NN * HD;
    float* aggs[4] = {agg0, agg1, agg2, agg3};

    hipMemsetAsync(deg, 0, (size_t)L_ * 4, stream);

    k_prep<<<12, 256, 0, stream>>>(rel_emb, W_rel, W_prop, b_prop, ra, out + (size_t)2 * NN * HD);
    k_proj<<<dim3(NN / 32, 4), 256, 0, stream>>>(feat, W_node, ra, e_src, e_dst, P);

    int eb = (4 * EE + 255) / 256;
    k_count<<<eb, 256, 0, stream>>>(dst, deg);
    k_scan1<<<NB_, 256, 0, stream>>>(deg, incl, bsum);
    k_scan2<<<1, 256, 0, stream>>>(bsum, bofs);
    k_scan3<<<NB_, 256, 0, stream>>>(deg, incl, bofs, offsets, cursor);
    k_fill<<<eb, 256, 0, stream>>>(src, dst, cursor, esorted);

    for (int r = 0; r < 4; ++r)
        k_node_msg<<<NN / 4, 256, 0, stream>>>(offsets, deg, esorted, e_src, e_dst, P, aggs[r], r);

    // type 0 (A): outs[1], outs[3]; type 1 (B): outs[0], outs[2]
    k_final<<<NN / 32, 256, 0, stream>>>(feat + (size_t)1 * NN * INF_, feat + (size_t)3 * NN * INF_,
                                         W_res, b_res, alpha + 0, Wx,
                                         agg1, agg3, out);
    k_final<<<NN / 32, 256, 0, stream>>>(feat + (size_t)0 * NN * INF_, feat + (size_t)2 * NN * INF_,
                                         W_res + (size_t)INF_ * HD, b_res + 256, alpha + 1, Wx + 256,
                                         agg0, agg2, out + (size_t)NN * HD);
}

// Round 4
// 929.069 us; speedup vs baseline: 9.5073x; 1.5301x over previous
//
#include <hip/hip_runtime.h>
#include <hip/hip_bf16.h>

#define NN 100000
#define EE 500000
#define H 8
#define D 32
#define INF_ 32
#define HD 256
#define SLOPE 0.2f
#define L_ (4 * NN)
#define NB_ ((L_ + 255) / 256)

typedef unsigned short u16;
typedef unsigned int u32;
typedef short bf16x8 __attribute__((ext_vector_type(8)));
typedef float f32x4 __attribute__((ext_vector_type(4)));

union U8 { uint4 u; bf16x8 v; };

__device__ __forceinline__ float leaky(float x) { return x >= 0.f ? x : SLOPE * x; }
__device__ __forceinline__ u16 bf16r(float x) {
    u32 u = __float_as_uint(x);
    u += 0x7fffu + ((u >> 16) & 1u);
    return (u16)(u >> 16);
}
__device__ __forceinline__ float bf16f(u16 v) { return __uint_as_float((u32)v << 16); }
__device__ __forceinline__ float blo(u32 w) { return __uint_as_float(w << 16); }
__device__ __forceinline__ float bhi(u32 w) { return __uint_as_float(w & 0xffff0000u); }
__device__ __forceinline__ u32 cvtpk(float lo, float hi) {
    u32 r;
    asm("v_cvt_pk_bf16_f32 %0, %1, %2" : "=v"(r) : "v"(lo), "v"(hi));
    return r;
}

// ---------------- tiny prep: ra[4][512] and rel_out[4][256] ----------------
__global__ void k_prep(const float* __restrict__ rel_emb, const float* __restrict__ W_rel,
                       const float* __restrict__ W_prop, const float* __restrict__ b_prop,
                       float* __restrict__ ra, float* __restrict__ rel_out) {
    int idx = blockIdx.x * blockDim.x + threadIdx.x;
    if (idx < 4 * 512) {
        int r = idx >> 9, o = idx & 511;
        float s = 0.f;
        #pragma unroll
        for (int i = 0; i < INF_; ++i) s += rel_emb[r * INF_ + i] * W_rel[(r * INF_ + i) * 512 + o];
        ra[idx] = s;
    } else if (idx < 4 * 512 + 4 * 256) {
        int j = idx - 2048;
        int r = j >> 8;
        float s = b_prop[j];
        #pragma unroll
        for (int i = 0; i < INF_; ++i) s += rel_emb[r * INF_ + i] * W_prop[(r * INF_ + i) * 256 + (j & 255)];
        rel_out[j] = s;
    }
}

// ---------------- build MFMA A-operand fragments (bf16) ----------------
// Layout: Wfrag[(q*17+ct)*512 + l*8 + b]   ct<16: A[i][k]=W_node[widx][k][ct*16+i]
//         ct==16: score rows: i<8 -> Wes_q[k][i], i>=8 -> Wed_q[k][i-8]
// Then WfragR[(ty*16+ct)*512 + l*8 + b] = W_res[ty][k][ct*16+i]   (offset 34816)
__global__ void k_wfrag(const float* __restrict__ W_node, const float* __restrict__ W_res,
                        const float* __restrict__ ra, u16* __restrict__ Wfrag) {
    int idx = blockIdx.x * 256 + threadIdx.x;
    if (idx >= 4 * 17 * 512 + 2 * 16 * 512) return;
    float v;
    if (idx < 4 * 17 * 512) {
        int q = idx / (17 * 512);
        int rem = idx - q * 17 * 512;
        int ct = rem >> 9;
        int lb = rem & 511;
        int l = lb >> 3, b = lb & 7;
        int k = (l >> 4) * 8 + b, i = l & 15;
        int rq = q ^ 1;
        const float* W = W_node + (size_t)(q & 1) * 32 * 256;
        if (ct < 16) {
            v = W[k * 256 + ct * 16 + i];
        } else {
            int h = i & 7;
            const float* rr = (i < 8) ? (ra + q * 512 + h * 64 + 32) : (ra + rq * 512 + h * 64);
            float s = 0.f;
            #pragma unroll
            for (int j = 0; j < 32; ++j) s += W[k * 256 + h * 32 + j] * rr[j];
            v = s;
        }
    } else {
        int idx2 = idx - 4 * 17 * 512;
        int ty = idx2 >> 13;            // 16*512 = 8192 per type
        int rem = idx2 & 8191;
        int ct = rem >> 9;
        int lb = rem & 511;
        int l = lb >> 3, b = lb & 7;
        int k = (l >> 4) * 8 + b, i = l & 15;
        v = W_res[(size_t)ty * 32 * 256 + k * 256 + ct * 16 + i];
    }
    Wfrag[idx] = bf16r(v);
}

// ---------------- MFMA projection: P (bf16, row-major [q][n][256]) + scores ----------------
__global__ __launch_bounds__(256) void k_proj_mfma(const float* __restrict__ feat,
                                                   const u16* __restrict__ Wfrag,
                                                   float* __restrict__ e_src,
                                                   float* __restrict__ e_dst,
                                                   u16* __restrict__ P) {
    const int q = blockIdx.y;
    const int rq = q ^ 1;               // REV[q]
    const int t = threadIdx.x, lane = t & 63;
    const int li = lane & 15, g = lane >> 4;
    const int wid = blockIdx.x * 4 + (t >> 6);
    const int nw = gridDim.x * 4;
    f32x4 zz = {0.f, 0.f, 0.f, 0.f};

    bf16x8 afr[17];
    #pragma unroll
    for (int ct = 0; ct < 17; ++ct) {
        U8 u;
        u.u = *(const uint4*)(Wfrag + (((size_t)q * 17 + ct) * 64 + lane) * 8);
        afr[ct] = u.v;
    }
    const float* F = feat + (size_t)rq * NN * INF_;   // feat[REV[q]]
    for (int tile = wid; tile < NN / 16; tile += nw) {
        const int node = tile * 16 + li;
        const float* fp = F + (size_t)node * 32 + g * 8;
        float4 f0 = *(const float4*)fp;
        float4 f1 = *(const float4*)(fp + 4);
        U8 b;
        b.u.x = cvtpk(f0.x, f0.y); b.u.y = cvtpk(f0.z, f0.w);
        b.u.z = cvtpk(f1.x, f1.y); b.u.w = cvtpk(f1.z, f1.w);
        u16* Pp = P + ((size_t)q * NN + node) * HD + g * 4;
        #pragma unroll
        for (int ct = 0; ct < 16; ++ct) {
            f32x4 acc = __builtin_amdgcn_mfma_f32_16x16x32_bf16(afr[ct], b.v, zz, 0, 0, 0);
            uint2 st;
            st.x = cvtpk(acc[0], acc[1]);
            st.y = cvtpk(acc[2], acc[3]);
            *(uint2*)(Pp + ct * 16) = st;
        }
        f32x4 sc = __builtin_amdgcn_mfma_f32_16x16x32_bf16(afr[16], b.v, zz, 0, 0, 0);
        float* sp = (g < 2) ? (e_src + ((size_t)q * NN + node) * 8 + (g & 1) * 4)
                            : (e_dst + ((size_t)rq * NN + node) * 8 + (g & 1) * 4);
        *(float4*)sp = make_float4(sc[0], sc[1], sc[2], sc[3]);
    }
}

// ---------------- CSR build ----------------
__global__ void k_count(const int* __restrict__ dst, u32* __restrict__ deg) {
    int idx = blockIdx.x * blockDim.x + threadIdx.x;
    if (idx >= 4 * EE) return;
    int r = idx / EE;
    atomicAdd(&deg[r * NN + dst[idx]], 1u);
}

__global__ void k_scan1(const u32* __restrict__ deg, u32* __restrict__ incl, u32* __restrict__ bsum) {
    __shared__ u32 sm[256];
    const int t = threadIdx.x;
    int i = blockIdx.x * 256 + t;
    u32 v = (i < L_) ? deg[i] : 0u;
    sm[t] = v;
    __syncthreads();
    for (int ofs = 1; ofs < 256; ofs <<= 1) {
        u32 x = (t >= ofs) ? sm[t - ofs] : 0u;
        __syncthreads();
        sm[t] += x;
        __syncthreads();
    }
    if (i < L_) incl[i] = sm[t];
    if (t == 255) bsum[blockIdx.x] = sm[255];
}

__global__ void k_scan2(const u32* __restrict__ bsum, u32* __restrict__ bofs) {
    __shared__ u32 sm[256];
    __shared__ u32 runS;
    const int t = threadIdx.x;
    if (t == 0) runS = 0u;
    __syncthreads();
    for (int c = 0; c < NB_; c += 256) {
        u32 v = (c + t < NB_) ? bsum[c + t] : 0u;
        sm[t] = v;
        __syncthreads();
        for (int ofs = 1; ofs < 256; ofs <<= 1) {
            u32 x = (t >= ofs) ? sm[t - ofs] : 0u;
            __syncthreads();
            sm[t] += x;
            __syncthreads();
        }
        u32 excl = sm[t] - v;
        if (c + t < NB_) bofs[c + t] = runS + excl;
        __syncthreads();
        if (t == 255) runS += sm[255];
        __syncthreads();
    }
}

__global__ void k_scan3(const u32* __restrict__ deg, const u32* __restrict__ incl,
                        const u32* __restrict__ bofs, u32* __restrict__ offsets,
                        u32* __restrict__ cursor) {
    int i = blockIdx.x * 256 + threadIdx.x;
    if (i >= L_) return;
    u32 excl = incl[i] - deg[i] + bofs[i >> 8];
    offsets[i] = excl;
    cursor[i] = excl;
}

__global__ void k_fill(const int* __restrict__ src, const int* __restrict__ dst,
                       u32* __restrict__ cursor, int* __restrict__ esorted) {
    int idx = blockIdx.x * blockDim.x + threadIdx.x;
    if (idx >= 4 * EE) return;
    int r = idx / EE;
    u32 pos = atomicAdd(&cursor[r * NN + dst[idx]], 1u);
    esorted[pos] = src[idx];
}

// ---------------- per-dst-node fused softmax + message aggregation ----------------
// one wave per (dst node, relation); no max pass (scores bounded ~|20|, f32 exp safe);
// software-pipelined gather; bf16 agg output.
__global__ __launch_bounds__(256) void k_node_msg(const u32* __restrict__ offsets,
                                                  const u32* __restrict__ deg,
                                                  const int* __restrict__ esorted,
                                                  const float* __restrict__ e_src,
                                                  const float* __restrict__ e_dst,
                                                  const u16* __restrict__ P,
                                                  u16* __restrict__ agg) {
    const int r = blockIdx.y;
    const int t = threadIdx.x, lane = t & 63;
    const int n = blockIdx.x * 4 + (t >> 6);
    const int h = lane >> 3;
    const int i = r * NN + n;
    const u32 off = offsets[i], dg = deg[i];
    u16* ap = agg + ((size_t)r * NN + n) * HD + lane * 4;
    if (dg == 0) {
        uint2 z2 = {0u, 0u};
        *(uint2*)ap = z2;
        return;
    }
    const float ed = e_dst[(size_t)i * 8 + h];
    const float* esr = e_src + (size_t)r * NN * 8;
    const u16* Pr = P + (size_t)r * NN * HD;
    int s = esorted[off];
    float es_n = esr[(size_t)s * 8 + h];
    ushort4 f_n = *(const ushort4*)(Pr + (size_t)s * HD + lane * 4);
    float z = 0.f, a0 = 0.f, a1 = 0.f, a2 = 0.f, a3 = 0.f;
    for (u32 k = 0; k < dg; ++k) {
        float es_c = es_n;
        ushort4 f_c = f_n;
        if (k + 1 < dg) {
            int s2 = esorted[off + k + 1];
            es_n = esr[(size_t)s2 * 8 + h];
            f_n = *(const ushort4*)(Pr + (size_t)s2 * HD + lane * 4);
        }
        float a = __expf(leaky(es_c + ed));
        z += a;
        a0 = fmaf(bf16f(f_c.x), a, a0);
        a1 = fmaf(bf16f(f_c.y), a, a1);
        a2 = fmaf(bf16f(f_c.z), a, a2);
        a3 = fmaf(bf16f(f_c.w), a, a3);
    }
    float inv = 1.f / z;
    uint2 st;
    st.x = cvtpk(a0 * inv, a1 * inv);
    st.y = cvtpk(a2 * inv, a3 * inv);
    *(uint2*)ap = st;
}

// ---------------- finalize (MFMA residual + crossing), both node types ----------------
__global__ __launch_bounds__(256) void k_final2(const float* __restrict__ feat,
                                                const u16* __restrict__ WfragR,
                                                const float* __restrict__ b_res,
                                                const float* __restrict__ alpha,
                                                const float* __restrict__ Wx,
                                                const u16* __restrict__ agg,
                                                float* __restrict__ outp) {
    const int ty = blockIdx.y;                 // 0: type A (rels 1,3)  1: type B (rels 0,2)
    const int rA = ty ? 0 : 1, rB = ty ? 2 : 3;
    const int t = threadIdx.x, lane = t & 63;
    const int li = lane & 15, g = lane >> 4;
    const int wid = blockIdx.x * 4 + (t >> 6);
    const int nw = gridDim.x * 4;
    const float ga = 1.f / (1.f + __expf(-alpha[ty]));
    const float gb = 1.f - ga;
    f32x4 zz = {0.f, 0.f, 0.f, 0.f};

    bf16x8 afr[16];
    #pragma unroll
    for (int ct = 0; ct < 16; ++ct) {
        U8 u;
        u.u = *(const uint4*)(WfragR + (((size_t)ty * 16 + ct) * 64 + lane) * 8);
        afr[ct] = u.v;
    }
    const float* FA = feat + (size_t)rA * NN * INF_;
    const float* FB = feat + (size_t)rB * NN * INF_;
    const u16* AG1 = agg + (size_t)rA * NN * HD;
    const u16* AG2 = agg + (size_t)rB * NN * HD;

    for (int tile = wid; tile < NN / 16; tile += nw) {
        const int node = tile * 16 + li;
        const float* fp1 = FA + (size_t)node * 32 + g * 8;
        const float* fp2 = FB + (size_t)node * 32 + g * 8;
        float4 x0 = *(const float4*)fp1, x1 = *(const float4*)(fp1 + 4);
        float4 y0 = *(const float4*)fp2, y1 = *(const float4*)(fp2 + 4);
        U8 b1, b2;
        b1.u.x = cvtpk(x0.x, x0.y); b1.u.y = cvtpk(x0.z, x0.w);
        b1.u.z = cvtpk(x1.x, x1.y); b1.u.w = cvtpk(x1.z, x1.w);
        b2.u.x = cvtpk(y0.x, y0.y); b2.u.y = cvtpk(y0.z, y0.w);
        b2.u.z = cvtpk(y1.x, y1.y); b2.u.w = cvtpk(y1.z, y1.w);

        float at1[8], at2[8];
        #pragma unroll
        for (int h = 0; h < 8; ++h) { at1[h] = 0.f; at2[h] = 0.f; }

        #pragma unroll
        for (int ct = 0; ct < 16; ++ct) {
            f32x4 r1 = __builtin_amdgcn_mfma_f32_16x16x32_bf16(afr[ct], b1.v, zz, 0, 0, 0);
            f32x4 r2 = __builtin_amdgcn_mfma_f32_16x16x32_bf16(afr[ct], b2.v, zz, 0, 0, 0);
            uint2 g1 = *(const uint2*)(AG1 + (size_t)node * HD + ct * 16 + g * 4);
            uint2 g2 = *(const uint2*)(AG2 + (size_t)node * HD + ct * 16 + g * 4);
            float4 bv = *(const float4*)(b_res + ty * 256 + ct * 16 + g * 4);
            float4 wv = *(const float4*)(Wx + ty * 256 + ct * 16 + g * 4);
            float o10 = fmaxf(blo(g1.x), 0.f) * ga + (r1[0] + bv.x) * gb;
            float o11 = fmaxf(bhi(g1.x), 0.f) * ga + (r1[1] + bv.y) * gb;
            float o12 = fmaxf(blo(g1.y), 0.f) * ga + (r1[2] + bv.z) * gb;
            float o13 = fmaxf(bhi(g1.y), 0.f) * ga + (r1[3] + bv.w) * gb;
            float o20 = fmaxf(blo(g2.x), 0.f) * ga + (r2[0] + bv.x) * gb;
            float o21 = fmaxf(bhi(g2.x), 0.f) * ga + (r2[1] + bv.y) * gb;
            float o22 = fmaxf(blo(g2.y), 0.f) * ga + (r2[2] + bv.z) * gb;
            float o23 = fmaxf(bhi(g2.y), 0.f) * ga + (r2[3] + bv.w) * gb;
            at1[ct >> 1] += o10 * wv.x + o11 * wv.y + o12 * wv.z + o13 * wv.w;
            at2[ct >> 1] += o20 * wv.x + o21 * wv.y + o22 * wv.z + o23 * wv.w;
        }
        #pragma unroll
        for (int h = 0; h < 8; ++h) {
            at1[h] += __shfl_xor(at1[h], 16, 64);
            at1[h] += __shfl_xor(at1[h], 32, 64);
            at2[h] += __shfl_xor(at2[h], 16, 64);
            at2[h] += __shfl_xor(at2[h], 32, 64);
        }
        float w1[8], w2[8];
        #pragma unroll
        for (int h = 0; h < 8; ++h) {
            float a1l = leaky(at1[h]), a2l = leaky(at2[h]);
            float mx = fmaxf(a1l, a2l);
            float e1 = __expf(a1l - mx), e2 = __expf(a2l - mx);
            float inv = 1.f / (e1 + e2);
            w1[h] = e1 * inv;
            w2[h] = e2 * inv;
        }
        float* op = outp + ((size_t)ty * NN + node) * HD;
        #pragma unroll
        for (int ct = 0; ct < 16; ++ct) {
            f32x4 r1 = __builtin_amdgcn_mfma_f32_16x16x32_bf16(afr[ct], b1.v, zz, 0, 0, 0);
            f32x4 r2 = __builtin_amdgcn_mfma_f32_16x16x32_bf16(afr[ct], b2.v, zz, 0, 0, 0);
            uint2 g1 = *(const uint2*)(AG1 + (size_t)node * HD + ct * 16 + g * 4);
            uint2 g2 = *(const uint2*)(AG2 + (size_t)node * HD + ct * 16 + g * 4);
            float4 bv = *(const float4*)(b_res + ty * 256 + ct * 16 + g * 4);
            float wa = w1[ct >> 1], wb = w2[ct >> 1];
            float4 o;
            o.x = (fmaxf(blo(g1.x), 0.f) * ga + (r1[0] + bv.x) * gb) * wa +
                  (fmaxf(blo(g2.x), 0.f) * ga + (r2[0] + bv.x) * gb) * wb;
            o.y = (fmaxf(bhi(g1.x), 0.f) * ga + (r1[1] + bv.y) * gb) * wa +
                  (fmaxf(bhi(g2.x), 0.f) * ga + (r2[1] + bv.y) * gb) * wb;
            o.z = (fmaxf(blo(g1.y), 0.f) * ga + (r1[2] + bv.z) * gb) * wa +
                  (fmaxf(blo(g2.y), 0.f) * ga + (r2[2] + bv.z) * gb) * wb;
            o.w = (fmaxf(bhi(g1.y), 0.f) * ga + (r1[3] + bv.w) * gb) * wa +
                  (fmaxf(bhi(g2.y), 0.f) * ga + (r2[3] + bv.w) * gb) * wb;
            *(float4*)(op + ct * 16 + g * 4) = o;
        }
    }
}

extern "C" void kernel_launch(void* const* d_in, const int* in_sizes, int n_in,
                              void* d_out, int out_size, void* d_ws, size_t ws_size,
                              hipStream_t stream) {
    const float* feat    = (const float*)d_in[0];
    const float* rel_emb = (const float*)d_in[1];
    const float* W_node  = (const float*)d_in[2];
    const float* W_rel   = (const float*)d_in[3];
    const float* W_prop  = (const float*)d_in[4];
    const float* b_prop  = (const float*)d_in[5];
    const float* W_res   = (const float*)d_in[6];
    const float* b_res   = (const float*)d_in[7];
    const float* alpha   = (const float*)d_in[8];
    const float* Wx      = (const float*)d_in[9];
    const int*   src     = (const int*)d_in[10];
    const int*   dst     = (const int*)d_in[11];
    float* out = (float*)d_out;

    // ws: ra | e_src | e_dst | P | Wfrag | deg | offsets | cursor | incl | bsum | bofs | esorted | agg
    char* ws = (char*)d_ws;
    float* ra      = (float*)ws;                            // 8 KB
    float* e_src   = (float*)(ws + 8192);                   // 12.8 MB
    float* e_dst   = e_src + (size_t)4 * NN * H;            // 12.8 MB
    u16*   P       = (u16*)(e_dst + (size_t)4 * NN * H);    // 204.8 MB
    u16*   Wfrag   = (u16*)((char*)P + (size_t)4 * NN * HD * 2);  // 102.4 KB
    u32*   deg     = (u32*)((char*)Wfrag + 102400);
    u32*   offsets = deg + L_;
    u32*   cursor  = offsets + L_;
    u32*   incl    = cursor + L_;
    u32*   bsum    = incl + L_;
    u32*   bofs    = bsum + 2048;
    int*   esorted = (int*)(bofs + 2048);                   // 8 MB
    u16*   agg     = (u16*)(esorted + (size_t)4 * EE);      // 204.8 MB (bf16, [4][NN][256])

    hipMemsetAsync(deg, 0, (size_t)L_ * 4, stream);

    k_prep<<<12, 256, 0, stream>>>(rel_emb, W_rel, W_prop, b_prop, ra, out + (size_t)2 * NN * HD);
    k_wfrag<<<200, 256, 0, stream>>>(W_node, W_res, ra, Wfrag);

    int eb = (4 * EE + 255) / 256;
    k_count<<<eb, 256, 0, stream>>>(dst, deg);
    k_scan1<<<NB_, 256, 0, stream>>>(deg, incl, bsum);
    k_scan2<<<1, 256, 0, stream>>>(bsum, bofs);
    k_scan3<<<NB_, 256, 0, stream>>>(deg, incl, bofs, offsets, cursor);
    k_fill<<<eb, 256, 0, stream>>>(src, dst, cursor, esorted);

    k_proj_mfma<<<dim3(512, 4), 256, 0, stream>>>(feat, Wfrag, e_src, e_dst, P);

    k_node_msg<<<dim3(NN / 4, 4), 256, 0, stream>>>(offsets, deg, esorted, e_src, e_dst, P, agg);

    k_final2<<<dim3(391, 2), 256, 0, stream>>>(feat, Wfrag + 4 * 17 * 512, b_res, alpha, Wx, agg, out);
}

// Round 5
// 856.394 us; speedup vs baseline: 10.3141x; 1.0849x over previous
//
#include <hip/hip_runtime.h>
#include <hip/hip_bf16.h>

#define NN 100000
#define EE 500000
#define H 8
#define D 32
#define INF_ 32
#define HD 256
#define SLOPE 0.2f
#define L_ (4 * NN)
#define NB_ ((L_ + 255) / 256)

typedef unsigned short u16;
typedef unsigned int u32;
typedef short bf16x8 __attribute__((ext_vector_type(8)));
typedef float f32x4 __attribute__((ext_vector_type(4)));

union U8 { uint4 u; bf16x8 v; };

__device__ __forceinline__ float leaky(float x) { return x >= 0.f ? x : SLOPE * x; }
__device__ __forceinline__ u16 bf16r(float x) {
    u32 u = __float_as_uint(x);
    u += 0x7fffu + ((u >> 16) & 1u);
    return (u16)(u >> 16);
}
__device__ __forceinline__ float bf16f(u16 v) { return __uint_as_float((u32)v << 16); }
__device__ __forceinline__ float blo(u32 w) { return __uint_as_float(w << 16); }
__device__ __forceinline__ float bhi(u32 w) { return __uint_as_float(w & 0xffff0000u); }
__device__ __forceinline__ u32 cvtpk(float lo, float hi) {
    u32 r;
    asm("v_cvt_pk_bf16_f32 %0, %1, %2" : "=v"(r) : "v"(lo), "v"(hi));
    return r;
}

// ---------------- tiny prep: ra[4][512] and rel_out[4][256] ----------------
__global__ void k_prep(const float* __restrict__ rel_emb, const float* __restrict__ W_rel,
                       const float* __restrict__ W_prop, const float* __restrict__ b_prop,
                       float* __restrict__ ra, float* __restrict__ rel_out) {
    int idx = blockIdx.x * blockDim.x + threadIdx.x;
    if (idx < 4 * 512) {
        int r = idx >> 9, o = idx & 511;
        float s = 0.f;
        #pragma unroll
        for (int i = 0; i < INF_; ++i) s += rel_emb[r * INF_ + i] * W_rel[(r * INF_ + i) * 512 + o];
        ra[idx] = s;
    } else if (idx < 4 * 512 + 4 * 256) {
        int j = idx - 2048;
        int r = j >> 8;
        float s = b_prop[j];
        #pragma unroll
        for (int i = 0; i < INF_; ++i) s += rel_emb[r * INF_ + i] * W_prop[(r * INF_ + i) * 256 + (j & 255)];
        rel_out[j] = s;
    }
}

// ---------------- build MFMA A-operand fragments (bf16) ----------------
__global__ void k_wfrag(const float* __restrict__ W_node, const float* __restrict__ W_res,
                        const float* __restrict__ ra, u16* __restrict__ Wfrag) {
    int idx = blockIdx.x * 256 + threadIdx.x;
    if (idx >= 4 * 17 * 512 + 2 * 16 * 512) return;
    float v;
    if (idx < 4 * 17 * 512) {
        int q = idx / (17 * 512);
        int rem = idx - q * 17 * 512;
        int ct = rem >> 9;
        int lb = rem & 511;
        int l = lb >> 3, b = lb & 7;
        int k = (l >> 4) * 8 + b, i = l & 15;
        int rq = q ^ 1;
        const float* W = W_node + (size_t)(q & 1) * 32 * 256;
        if (ct < 16) {
            v = W[k * 256 + ct * 16 + i];
        } else {
            int h = i & 7;
            const float* rr = (i < 8) ? (ra + q * 512 + h * 64 + 32) : (ra + rq * 512 + h * 64);
            float s = 0.f;
            #pragma unroll
            for (int j = 0; j < 32; ++j) s += W[k * 256 + h * 32 + j] * rr[j];
            v = s;
        }
    } else {
        int idx2 = idx - 4 * 17 * 512;
        int ty = idx2 >> 13;
        int rem = idx2 & 8191;
        int ct = rem >> 9;
        int lb = rem & 511;
        int l = lb >> 3, b = lb & 7;
        int k = (l >> 4) * 8 + b, i = l & 15;
        v = W_res[(size_t)ty * 32 * 256 + k * 256 + ct * 16 + i];
    }
    Wfrag[idx] = bf16r(v);
}

// ---------------- MFMA projection: P (bf16, row-major [q][n][256]) + scores ----------------
__global__ __launch_bounds__(256) void k_proj_mfma(const float* __restrict__ feat,
                                                   const u16* __restrict__ Wfrag,
                                                   float* __restrict__ e_src,
                                                   float* __restrict__ e_dst,
                                                   u16* __restrict__ P) {
    const int q = blockIdx.y;
    const int rq = q ^ 1;
    const int t = threadIdx.x, lane = t & 63;
    const int li = lane & 15, g = lane >> 4;
    const int wid = blockIdx.x * 4 + (t >> 6);
    const int nw = gridDim.x * 4;
    f32x4 zz = {0.f, 0.f, 0.f, 0.f};

    bf16x8 afr[17];
    #pragma unroll
    for (int ct = 0; ct < 17; ++ct) {
        U8 u;
        u.u = *(const uint4*)(Wfrag + (((size_t)q * 17 + ct) * 64 + lane) * 8);
        afr[ct] = u.v;
    }
    const float* F = feat + (size_t)rq * NN * INF_;
    for (int tile = wid; tile < NN / 16; tile += nw) {
        const int node = tile * 16 + li;
        const float* fp = F + (size_t)node * 32 + g * 8;
        float4 f0 = *(const float4*)fp;
        float4 f1 = *(const float4*)(fp + 4);
        U8 b;
        b.u.x = cvtpk(f0.x, f0.y); b.u.y = cvtpk(f0.z, f0.w);
        b.u.z = cvtpk(f1.x, f1.y); b.u.w = cvtpk(f1.z, f1.w);
        u16* Pp = P + ((size_t)q * NN + node) * HD + g * 4;
        #pragma unroll
        for (int ct = 0; ct < 16; ++ct) {
            f32x4 acc = __builtin_amdgcn_mfma_f32_16x16x32_bf16(afr[ct], b.v, zz, 0, 0, 0);
            uint2 st;
            st.x = cvtpk(acc[0], acc[1]);
            st.y = cvtpk(acc[2], acc[3]);
            *(uint2*)(Pp + ct * 16) = st;
        }
        f32x4 sc = __builtin_amdgcn_mfma_f32_16x16x32_bf16(afr[16], b.v, zz, 0, 0, 0);
        float* sp = (g < 2) ? (e_src + ((size_t)q * NN + node) * 8 + (g & 1) * 4)
                            : (e_dst + ((size_t)rq * NN + node) * 8 + (g & 1) * 4);
        *(float4*)sp = make_float4(sc[0], sc[1], sc[2], sc[3]);
    }
}

// ---------------- CSR build ----------------
__global__ void k_count(const int* __restrict__ dst, u32* __restrict__ deg) {
    int idx = blockIdx.x * blockDim.x + threadIdx.x;
    if (idx >= 4 * EE) return;
    int r = idx / EE;
    atomicAdd(&deg[r * NN + dst[idx]], 1u);
}

__global__ void k_scan1(const u32* __restrict__ deg, u32* __restrict__ incl, u32* __restrict__ bsum) {
    __shared__ u32 sm[256];
    const int t = threadIdx.x;
    int i = blockIdx.x * 256 + t;
    u32 v = (i < L_) ? deg[i] : 0u;
    sm[t] = v;
    __syncthreads();
    for (int ofs = 1; ofs < 256; ofs <<= 1) {
        u32 x = (t >= ofs) ? sm[t - ofs] : 0u;
        __syncthreads();
        sm[t] += x;
        __syncthreads();
    }
    if (i < L_) incl[i] = sm[t];
    if (t == 255) bsum[blockIdx.x] = sm[255];
}

__global__ void k_scan2(const u32* __restrict__ bsum, u32* __restrict__ bofs) {
    __shared__ u32 sm[256];
    __shared__ u32 runS;
    const int t = threadIdx.x;
    if (t == 0) runS = 0u;
    __syncthreads();
    for (int c = 0; c < NB_; c += 256) {
        u32 v = (c + t < NB_) ? bsum[c + t] : 0u;
        sm[t] = v;
        __syncthreads();
        for (int ofs = 1; ofs < 256; ofs <<= 1) {
            u32 x = (t >= ofs) ? sm[t - ofs] : 0u;
            __syncthreads();
            sm[t] += x;
            __syncthreads();
        }
        u32 excl = sm[t] - v;
        if (c + t < NB_) bofs[c + t] = runS + excl;
        __syncthreads();
        if (t == 255) runS += sm[255];
        __syncthreads();
    }
}

__global__ void k_scan3(const u32* __restrict__ deg, const u32* __restrict__ incl,
                        const u32* __restrict__ bofs, u32* __restrict__ offsets,
                        u32* __restrict__ cursor) {
    int i = blockIdx.x * 256 + threadIdx.x;
    if (i >= L_) return;
    u32 excl = incl[i] - deg[i] + bofs[i >> 8];
    offsets[i] = excl;
    cursor[i] = excl;
}

__global__ void k_fill(const int* __restrict__ src, const int* __restrict__ dst,
                       u32* __restrict__ cursor, int* __restrict__ esorted) {
    int idx = blockIdx.x * blockDim.x + threadIdx.x;
    if (idx >= 4 * EE) return;
    int r = idx / EE;
    u32 pos = atomicAdd(&cursor[r * NN + dst[idx]], 1u);
    esorted[pos] = src[idx];
}

// ---------------- per-dst-node fused softmax + message aggregation ----------------
// one wave per (dst node, relation); 4-wide edge batching for 4-deep MLP on the
// dependent index->row gather chain; wave-uniform tail guards (no divergence).
__global__ __launch_bounds__(256) void k_node_msg(const u32* __restrict__ offsets,
                                                  const u32* __restrict__ deg,
                                                  const int* __restrict__ esorted,
                                                  const float* __restrict__ e_src,
                                                  const float* __restrict__ e_dst,
                                                  const u16* __restrict__ P,
                                                  u16* __restrict__ agg) {
    const int r = blockIdx.y;
    const int t = threadIdx.x, lane = t & 63;
    const int n = blockIdx.x * 4 + (t >> 6);
    const int h = lane >> 3;
    const int i = r * NN + n;
    const u32 off = offsets[i], dg = deg[i];
    u16* ap = agg + ((size_t)r * NN + n) * HD + lane * 4;
    if (dg == 0) {
        uint2 z2 = {0u, 0u};
        *(uint2*)ap = z2;
        return;
    }
    const float ed = e_dst[(size_t)i * 8 + h];
    const float* esr = e_src + (size_t)r * NN * 8;
    const u16* Pr = P + (size_t)r * NN * HD;
    float z = 0.f, a0 = 0.f, a1 = 0.f, a2 = 0.f, a3 = 0.f;
    const int sd = esorted[off];
    for (u32 k = 0; k < dg; k += 4) {
        int s0 = esorted[off + k];
        int s1 = (k + 1u < dg) ? esorted[off + k + 1] : sd;
        int s2 = (k + 2u < dg) ? esorted[off + k + 2] : sd;
        int s3 = (k + 3u < dg) ? esorted[off + k + 3] : sd;
        float e0 = esr[(size_t)s0 * 8 + h];
        float e1 = esr[(size_t)s1 * 8 + h];
        float e2 = esr[(size_t)s2 * 8 + h];
        float e3 = esr[(size_t)s3 * 8 + h];
        ushort4 f0 = *(const ushort4*)(Pr + (size_t)s0 * HD + lane * 4);
        ushort4 f1 = *(const ushort4*)(Pr + (size_t)s1 * HD + lane * 4);
        ushort4 f2 = *(const ushort4*)(Pr + (size_t)s2 * HD + lane * 4);
        ushort4 f3 = *(const ushort4*)(Pr + (size_t)s3 * HD + lane * 4);
        float w0 = __expf(leaky(e0 + ed));
        float w1 = (k + 1u < dg) ? __expf(leaky(e1 + ed)) : 0.f;
        float w2 = (k + 2u < dg) ? __expf(leaky(e2 + ed)) : 0.f;
        float w3 = (k + 3u < dg) ? __expf(leaky(e3 + ed)) : 0.f;
        z += (w0 + w1) + (w2 + w3);
        a0 = fmaf(bf16f(f0.x), w0, a0); a1 = fmaf(bf16f(f0.y), w0, a1);
        a2 = fmaf(bf16f(f0.z), w0, a2); a3 = fmaf(bf16f(f0.w), w0, a3);
        a0 = fmaf(bf16f(f1.x), w1, a0); a1 = fmaf(bf16f(f1.y), w1, a1);
        a2 = fmaf(bf16f(f1.z), w1, a2); a3 = fmaf(bf16f(f1.w), w1, a3);
        a0 = fmaf(bf16f(f2.x), w2, a0); a1 = fmaf(bf16f(f2.y), w2, a1);
        a2 = fmaf(bf16f(f2.z), w2, a2); a3 = fmaf(bf16f(f2.w), w2, a3);
        a0 = fmaf(bf16f(f3.x), w3, a0); a1 = fmaf(bf16f(f3.y), w3, a1);
        a2 = fmaf(bf16f(f3.z), w3, a2); a3 = fmaf(bf16f(f3.w), w3, a3);
    }
    float inv = 1.f / z;
    uint2 st;
    st.x = cvtpk(a0 * inv, a1 * inv);
    st.y = cvtpk(a2 * inv, a3 * inv);
    *(uint2*)ap = st;
}

// ---------------- finalize (MFMA residual + crossing), both node types ----------------
__global__ __launch_bounds__(256) void k_final2(const float* __restrict__ feat,
                                                const u16* __restrict__ WfragR,
                                                const float* __restrict__ b_res,
                                                const float* __restrict__ alpha,
                                                const float* __restrict__ Wx,
                                                const u16* __restrict__ agg,
                                                float* __restrict__ outp) {
    const int ty = blockIdx.y;
    const int rA = ty ? 0 : 1, rB = ty ? 2 : 3;
    const int t = threadIdx.x, lane = t & 63;
    const int li = lane & 15, g = lane >> 4;
    const int wid = blockIdx.x * 4 + (t >> 6);
    const int nw = gridDim.x * 4;
    const float ga = 1.f / (1.f + __expf(-alpha[ty]));
    const float gb = 1.f - ga;
    f32x4 zz = {0.f, 0.f, 0.f, 0.f};

    bf16x8 afr[16];
    #pragma unroll
    for (int ct = 0; ct < 16; ++ct) {
        U8 u;
        u.u = *(const uint4*)(WfragR + (((size_t)ty * 16 + ct) * 64 + lane) * 8);
        afr[ct] = u.v;
    }
    const float* FA = feat + (size_t)rA * NN * INF_;
    const float* FB = feat + (size_t)rB * NN * INF_;
    const u16* AG1 = agg + (size_t)rA * NN * HD;
    const u16* AG2 = agg + (size_t)rB * NN * HD;

    for (int tile = wid; tile < NN / 16; tile += nw) {
        const int node = tile * 16 + li;
        const float* fp1 = FA + (size_t)node * 32 + g * 8;
        const float* fp2 = FB + (size_t)node * 32 + g * 8;
        float4 x0 = *(const float4*)fp1, x1 = *(const float4*)(fp1 + 4);
        float4 y0 = *(const float4*)fp2, y1 = *(const float4*)(fp2 + 4);
        U8 b1, b2;
        b1.u.x = cvtpk(x0.x, x0.y); b1.u.y = cvtpk(x0.z, x0.w);
        b1.u.z = cvtpk(x1.x, x1.y); b1.u.w = cvtpk(x1.z, x1.w);
        b2.u.x = cvtpk(y0.x, y0.y); b2.u.y = cvtpk(y0.z, y0.w);
        b2.u.z = cvtpk(y1.x, y1.y); b2.u.w = cvtpk(y1.z, y1.w);

        float at1[8], at2[8];
        #pragma unroll
        for (int h = 0; h < 8; ++h) { at1[h] = 0.f; at2[h] = 0.f; }

        #pragma unroll
        for (int ct = 0; ct < 16; ++ct) {
            f32x4 r1 = __builtin_amdgcn_mfma_f32_16x16x32_bf16(afr[ct], b1.v, zz, 0, 0, 0);
            f32x4 r2 = __builtin_amdgcn_mfma_f32_16x16x32_bf16(afr[ct], b2.v, zz, 0, 0, 0);
            uint2 g1 = *(const uint2*)(AG1 + (size_t)node * HD + ct * 16 + g * 4);
            uint2 g2 = *(const uint2*)(AG2 + (size_t)node * HD + ct * 16 + g * 4);
            float4 bv = *(const float4*)(b_res + ty * 256 + ct * 16 + g * 4);
            float4 wv = *(const float4*)(Wx + ty * 256 + ct * 16 + g * 4);
            float o10 = fmaxf(blo(g1.x), 0.f) * ga + (r1[0] + bv.x) * gb;
            float o11 = fmaxf(bhi(g1.x), 0.f) * ga + (r1[1] + bv.y) * gb;
            float o12 = fmaxf(blo(g1.y), 0.f) * ga + (r1[2] + bv.z) * gb;
            float o13 = fmaxf(bhi(g1.y), 0.f) * ga + (r1[3] + bv.w) * gb;
            float o20 = fmaxf(blo(g2.x), 0.f) * ga + (r2[0] + bv.x) * gb;
            float o21 = fmaxf(bhi(g2.x), 0.f) * ga + (r2[1] + bv.y) * gb;
            float o22 = fmaxf(blo(g2.y), 0.f) * ga + (r2[2] + bv.z) * gb;
            float o23 = fmaxf(bhi(g2.y), 0.f) * ga + (r2[3] + bv.w) * gb;
            at1[ct >> 1] += o10 * wv.x + o11 * wv.y + o12 * wv.z + o13 * wv.w;
            at2[ct >> 1] += o20 * wv.x + o21 * wv.y + o22 * wv.z + o23 * wv.w;
        }
        #pragma unroll
        for (int h = 0; h < 8; ++h) {
            at1[h] += __shfl_xor(at1[h], 16, 64);
            at1[h] += __shfl_xor(at1[h], 32, 64);
            at2[h] += __shfl_xor(at2[h], 16, 64);
            at2[h] += __shfl_xor(at2[h], 32, 64);
        }
        float w1[8], w2[8];
        #pragma unroll
        for (int h = 0; h < 8; ++h) {
            float a1l = leaky(at1[h]), a2l = leaky(at2[h]);
            float mx = fmaxf(a1l, a2l);
            float e1 = __expf(a1l - mx), e2 = __expf(a2l - mx);
            float inv = 1.f / (e1 + e2);
            w1[h] = e1 * inv;
            w2[h] = e2 * inv;
        }
        float* op = outp + ((size_t)ty * NN + node) * HD;
        #pragma unroll
        for (int ct = 0; ct < 16; ++ct) {
            f32x4 r1 = __builtin_amdgcn_mfma_f32_16x16x32_bf16(afr[ct], b1.v, zz, 0, 0, 0);
            f32x4 r2 = __builtin_amdgcn_mfma_f32_16x16x32_bf16(afr[ct], b2.v, zz, 0, 0, 0);
            uint2 g1 = *(const uint2*)(AG1 + (size_t)node * HD + ct * 16 + g * 4);
            uint2 g2 = *(const uint2*)(AG2 + (size_t)node * HD + ct * 16 + g * 4);
            float4 bv = *(const float4*)(b_res + ty * 256 + ct * 16 + g * 4);
            float wa = w1[ct >> 1], wb = w2[ct >> 1];
            float4 o;
            o.x = (fmaxf(blo(g1.x), 0.f) * ga + (r1[0] + bv.x) * gb) * wa +
                  (fmaxf(blo(g2.x), 0.f) * ga + (r2[0] + bv.x) * gb) * wb;
            o.y = (fmaxf(bhi(g1.x), 0.f) * ga + (r1[1] + bv.y) * gb) * wa +
                  (fmaxf(bhi(g2.x), 0.f) * ga + (r2[1] + bv.y) * gb) * wb;
            o.z = (fmaxf(blo(g1.y), 0.f) * ga + (r1[2] + bv.z) * gb) * wa +
                  (fmaxf(blo(g2.y), 0.f) * ga + (r2[2] + bv.z) * gb) * wb;
            o.w = (fmaxf(bhi(g1.y), 0.f) * ga + (r1[3] + bv.w) * gb) * wa +
                  (fmaxf(bhi(g2.y), 0.f) * ga + (r2[3] + bv.w) * gb) * wb;
            *(float4*)(op + ct * 16 + g * 4) = o;
        }
    }
}

extern "C" void kernel_launch(void* const* d_in, const int* in_sizes, int n_in,
                              void* d_out, int out_size, void* d_ws, size_t ws_size,
                              hipStream_t stream) {
    const float* feat    = (const float*)d_in[0];
    const float* rel_emb = (const float*)d_in[1];
    const float* W_node  = (const float*)d_in[2];
    const float* W_rel   = (const float*)d_in[3];
    const float* W_prop  = (const float*)d_in[4];
    const float* b_prop  = (const float*)d_in[5];
    const float* W_res   = (const float*)d_in[6];
    const float* b_res   = (const float*)d_in[7];
    const float* alpha   = (const float*)d_in[8];
    const float* Wx      = (const float*)d_in[9];
    const int*   src     = (const int*)d_in[10];
    const int*   dst     = (const int*)d_in[11];
    float* out = (float*)d_out;

    // ws: ra | e_src | e_dst | P | Wfrag | deg | offsets | cursor | incl | bsum | bofs | esorted | agg
    char* ws = (char*)d_ws;
    float* ra      = (float*)ws;                            // 8 KB
    float* e_src   = (float*)(ws + 8192);                   // 12.8 MB
    float* e_dst   = e_src + (size_t)4 * NN * H;            // 12.8 MB
    u16*   P       = (u16*)(e_dst + (size_t)4 * NN * H);    // 204.8 MB
    u16*   Wfrag   = (u16*)((char*)P + (size_t)4 * NN * HD * 2);  // 102.4 KB
    u32*   deg     = (u32*)((char*)Wfrag + 102400);
    u32*   offsets = deg + L_;
    u32*   cursor  = offsets + L_;
    u32*   incl    = cursor + L_;
    u32*   bsum    = incl + L_;
    u32*   bofs    = bsum + 2048;
    int*   esorted = (int*)(bofs + 2048);                   // 8 MB
    u16*   agg     = (u16*)(esorted + (size_t)4 * EE);      // 204.8 MB (bf16, [4][NN][256])

    hipMemsetAsync(deg, 0, (size_t)L_ * 4, stream);

    k_prep<<<12, 256, 0, stream>>>(rel_emb, W_rel, W_prop, b_prop, ra, out + (size_t)2 * NN * HD);
    k_wfrag<<<200, 256, 0, stream>>>(W_node, W_res, ra, Wfrag);

    int eb = (4 * EE + 255) / 256;
    k_count<<<eb, 256, 0, stream>>>(dst, deg);
    k_scan1<<<NB_, 256, 0, stream>>>(deg, incl, bsum);
    k_scan2<<<1, 256, 0, stream>>>(bsum, bofs);
    k_scan3<<<NB_, 256, 0, stream>>>(deg, incl, bofs, offsets, cursor);
    k_fill<<<eb, 256, 0, stream>>>(src, dst, cursor, esorted);

    k_proj_mfma<<<dim3(512, 4), 256, 0, stream>>>(feat, Wfrag, e_src, e_dst, P);

    k_node_msg<<<dim3(NN / 4, 4), 256, 0, stream>>>(offsets, deg, esorted, e_src, e_dst, P, agg);

    k_final2<<<dim3(391, 2), 256, 0, stream>>>(feat, Wfrag + 4 * 17 * 512, b_res, alpha, Wx, agg, out);
}

// Round 6
// 838.037 us; speedup vs baseline: 10.5401x; 1.0219x over previous
//
#include <hip/hip_runtime.h>
#include <hip/hip_bf16.h>

#define NN 100000
#define EE 500000
#define H 8
#define D 32
#define INF_ 32
#define HD 256
#define SLOPE 0.2f
#define L_ (4 * NN)
#define NB_ ((L_ + 255) / 256)

typedef unsigned short u16;
typedef unsigned int u32;
typedef short bf16x8 __attribute__((ext_vector_type(8)));
typedef float f32x4 __attribute__((ext_vector_type(4)));

union U8 { uint4 u; bf16x8 v; };

__device__ __forceinline__ float leaky(float x) { return x >= 0.f ? x : SLOPE * x; }
__device__ __forceinline__ u16 bf16r(float x) {
    u32 u = __float_as_uint(x);
    u += 0x7fffu + ((u >> 16) & 1u);
    return (u16)(u >> 16);
}
__device__ __forceinline__ float bf16f(u16 v) { return __uint_as_float((u32)v << 16); }
__device__ __forceinline__ float blo(u32 w) { return __uint_as_float(w << 16); }
__device__ __forceinline__ float bhi(u32 w) { return __uint_as_float(w & 0xffff0000u); }
__device__ __forceinline__ u32 cvtpk(float lo, float hi) {
    u32 r;
    asm("v_cvt_pk_bf16_f32 %0, %1, %2" : "=v"(r) : "v"(lo), "v"(hi));
    return r;
}

// ---------------- tiny prep: ra[4][512] and rel_out[4][256] ----------------
__global__ void k_prep(const float* __restrict__ rel_emb, const float* __restrict__ W_rel,
                       const float* __restrict__ W_prop, const float* __restrict__ b_prop,
                       float* __restrict__ ra, float* __restrict__ rel_out) {
    int idx = blockIdx.x * blockDim.x + threadIdx.x;
    if (idx < 4 * 512) {
        int r = idx >> 9, o = idx & 511;
        float s = 0.f;
        #pragma unroll
        for (int i = 0; i < INF_; ++i) s += rel_emb[r * INF_ + i] * W_rel[(r * INF_ + i) * 512 + o];
        ra[idx] = s;
    } else if (idx < 4 * 512 + 4 * 256) {
        int j = idx - 2048;
        int r = j >> 8;
        float s = b_prop[j];
        #pragma unroll
        for (int i = 0; i < INF_; ++i) s += rel_emb[r * INF_ + i] * W_prop[(r * INF_ + i) * 256 + (j & 255)];
        rel_out[j] = s;
    }
}

// ---------------- build MFMA A-operand fragments (bf16) ----------------
__global__ void k_wfrag(const float* __restrict__ W_node, const float* __restrict__ W_res,
                        const float* __restrict__ ra, u16* __restrict__ Wfrag) {
    int idx = blockIdx.x * 256 + threadIdx.x;
    if (idx >= 4 * 17 * 512 + 2 * 16 * 512) return;
    float v;
    if (idx < 4 * 17 * 512) {
        int q = idx / (17 * 512);
        int rem = idx - q * 17 * 512;
        int ct = rem >> 9;
        int lb = rem & 511;
        int l = lb >> 3, b = lb & 7;
        int k = (l >> 4) * 8 + b, i = l & 15;
        int rq = q ^ 1;
        const float* W = W_node + (size_t)(q & 1) * 32 * 256;
        if (ct < 16) {
            v = W[k * 256 + ct * 16 + i];
        } else {
            int h = i & 7;
            const float* rr = (i < 8) ? (ra + q * 512 + h * 64 + 32) : (ra + rq * 512 + h * 64);
            float s = 0.f;
            #pragma unroll
            for (int j = 0; j < 32; ++j) s += W[k * 256 + h * 32 + j] * rr[j];
            v = s;
        }
    } else {
        int idx2 = idx - 4 * 17 * 512;
        int ty = idx2 >> 13;
        int rem = idx2 & 8191;
        int ct = rem >> 9;
        int lb = rem & 511;
        int l = lb >> 3, b = lb & 7;
        int k = (l >> 4) * 8 + b, i = l & 15;
        v = W_res[(size_t)ty * 32 * 256 + k * 256 + ct * 16 + i];
    }
    Wfrag[idx] = bf16r(v);
}

// ---------------- MFMA projection: P (bf16, row-major [q][n][256]) + scores ----------------
__global__ __launch_bounds__(256) void k_proj_mfma(const float* __restrict__ feat,
                                                   const u16* __restrict__ Wfrag,
                                                   float* __restrict__ e_src,
                                                   float* __restrict__ e_dst,
                                                   u16* __restrict__ P) {
    const int q = blockIdx.y;
    const int rq = q ^ 1;
    const int t = threadIdx.x, lane = t & 63;
    const int li = lane & 15, g = lane >> 4;
    const int wid = blockIdx.x * 4 + (t >> 6);
    const int nw = gridDim.x * 4;
    f32x4 zz = {0.f, 0.f, 0.f, 0.f};

    bf16x8 afr[17];
    #pragma unroll
    for (int ct = 0; ct < 17; ++ct) {
        U8 u;
        u.u = *(const uint4*)(Wfrag + (((size_t)q * 17 + ct) * 64 + lane) * 8);
        afr[ct] = u.v;
    }
    const float* F = feat + (size_t)rq * NN * INF_;
    for (int tile = wid; tile < NN / 16; tile += nw) {
        const int node = tile * 16 + li;
        const float* fp = F + (size_t)node * 32 + g * 8;
        float4 f0 = *(const float4*)fp;
        float4 f1 = *(const float4*)(fp + 4);
        U8 b;
        b.u.x = cvtpk(f0.x, f0.y); b.u.y = cvtpk(f0.z, f0.w);
        b.u.z = cvtpk(f1.x, f1.y); b.u.w = cvtpk(f1.z, f1.w);
        u16* Pp = P + ((size_t)q * NN + node) * HD + g * 4;
        #pragma unroll
        for (int ct = 0; ct < 16; ++ct) {
            f32x4 acc = __builtin_amdgcn_mfma_f32_16x16x32_bf16(afr[ct], b.v, zz, 0, 0, 0);
            uint2 st;
            st.x = cvtpk(acc[0], acc[1]);
            st.y = cvtpk(acc[2], acc[3]);
            *(uint2*)(Pp + ct * 16) = st;
        }
        f32x4 sc = __builtin_amdgcn_mfma_f32_16x16x32_bf16(afr[16], b.v, zz, 0, 0, 0);
        float* sp = (g < 2) ? (e_src + ((size_t)q * NN + node) * 8 + (g & 1) * 4)
                            : (e_dst + ((size_t)rq * NN + node) * 8 + (g & 1) * 4);
        *(float4*)sp = make_float4(sc[0], sc[1], sc[2], sc[3]);
    }
}

// ---------------- CSR build ----------------
__global__ void k_count(const int* __restrict__ dst, u32* __restrict__ deg) {
    int idx = blockIdx.x * blockDim.x + threadIdx.x;
    if (idx >= 4 * EE) return;
    int r = idx / EE;
    atomicAdd(&deg[r * NN + dst[idx]], 1u);
}

__global__ void k_scan1(const u32* __restrict__ deg, u32* __restrict__ incl, u32* __restrict__ bsum) {
    __shared__ u32 sm[256];
    const int t = threadIdx.x;
    int i = blockIdx.x * 256 + t;
    u32 v = (i < L_) ? deg[i] : 0u;
    sm[t] = v;
    __syncthreads();
    for (int ofs = 1; ofs < 256; ofs <<= 1) {
        u32 x = (t >= ofs) ? sm[t - ofs] : 0u;
        __syncthreads();
        sm[t] += x;
        __syncthreads();
    }
    if (i < L_) incl[i] = sm[t];
    if (t == 255) bsum[blockIdx.x] = sm[255];
}

__global__ void k_scan2(const u32* __restrict__ bsum, u32* __restrict__ bofs) {
    __shared__ u32 sm[256];
    __shared__ u32 runS;
    const int t = threadIdx.x;
    if (t == 0) runS = 0u;
    __syncthreads();
    for (int c = 0; c < NB_; c += 256) {
        u32 v = (c + t < NB_) ? bsum[c + t] : 0u;
        sm[t] = v;
        __syncthreads();
        for (int ofs = 1; ofs < 256; ofs <<= 1) {
            u32 x = (t >= ofs) ? sm[t - ofs] : 0u;
            __syncthreads();
            sm[t] += x;
            __syncthreads();
        }
        u32 excl = sm[t] - v;
        if (c + t < NB_) bofs[c + t] = runS + excl;
        __syncthreads();
        if (t == 255) runS += sm[255];
        __syncthreads();
    }
}

__global__ void k_scan3(const u32* __restrict__ deg, const u32* __restrict__ incl,
                        const u32* __restrict__ bofs, u32* __restrict__ offsets,
                        u32* __restrict__ cursor) {
    int i = blockIdx.x * 256 + threadIdx.x;
    if (i >= L_) return;
    u32 excl = incl[i] - deg[i] + bofs[i >> 8];
    offsets[i] = excl;
    cursor[i] = excl;
}

__global__ void k_fill(const int* __restrict__ src, const int* __restrict__ dst,
                       u32* __restrict__ cursor, int* __restrict__ esorted) {
    int idx = blockIdx.x * blockDim.x + threadIdx.x;
    if (idx >= 4 * EE) return;
    int r = idx / EE;
    u32 pos = atomicAdd(&cursor[r * NN + dst[idx]], 1u);
    esorted[pos] = src[idx];
}

// ---------------- per-dst-node fused softmax + message aggregation ----------------
// one wave per (dst node, relation); 8-wide edge batching: with avg degree ~5,
// ~93% of nodes complete in ONE batch -> 16 independent gathers in flight.
// Guarded lanes clamp index to the node's first src (L1-hit dup row, weight=0).
__global__ __launch_bounds__(256) void k_node_msg(const u32* __restrict__ offsets,
                                                  const u32* __restrict__ deg,
                                                  const int* __restrict__ esorted,
                                                  const float* __restrict__ e_src,
                                                  const float* __restrict__ e_dst,
                                                  const u16* __restrict__ P,
                                                  u16* __restrict__ agg) {
    const int r = blockIdx.y;
    const int t = threadIdx.x, lane = t & 63;
    const int n = blockIdx.x * 4 + (t >> 6);
    const int h = lane >> 3;
    const int i = r * NN + n;
    const u32 off = offsets[i], dg = deg[i];
    u16* ap = agg + ((size_t)r * NN + n) * HD + lane * 4;
    if (dg == 0) {
        uint2 z2 = {0u, 0u};
        *(uint2*)ap = z2;
        return;
    }
    const float ed = e_dst[(size_t)i * 8 + h];
    const float* esr = e_src + (size_t)r * NN * 8;
    const u16* Pr = P + (size_t)r * NN * HD;
    float z = 0.f, a0 = 0.f, a1 = 0.f, a2 = 0.f, a3 = 0.f;
    const int sd = esorted[off];
    for (u32 k = 0; k < dg; k += 8) {
        int s[8];
        s[0] = esorted[off + k];
        #pragma unroll
        for (int j = 1; j < 8; ++j) s[j] = (k + j < dg) ? esorted[off + k + j] : sd;
        float e[8];
        ushort4 f[8];
        #pragma unroll
        for (int j = 0; j < 8; ++j) {
            e[j] = esr[(size_t)s[j] * 8 + h];
            f[j] = *(const ushort4*)(Pr + (size_t)s[j] * HD + lane * 4);
        }
        float w[8];
        w[0] = __expf(leaky(e[0] + ed));
        #pragma unroll
        for (int j = 1; j < 8; ++j)
            w[j] = (k + j < dg) ? __expf(leaky(e[j] + ed)) : 0.f;
        #pragma unroll
        for (int j = 0; j < 8; ++j) {
            z += w[j];
            a0 = fmaf(bf16f(f[j].x), w[j], a0);
            a1 = fmaf(bf16f(f[j].y), w[j], a1);
            a2 = fmaf(bf16f(f[j].z), w[j], a2);
            a3 = fmaf(bf16f(f[j].w), w[j], a3);
        }
    }
    float inv = 1.f / z;
    uint2 st;
    st.x = cvtpk(a0 * inv, a1 * inv);
    st.y = cvtpk(a2 * inv, a3 * inv);
    *(uint2*)ap = st;
}

// ---------------- finalize (MFMA residual + crossing), both node types ----------------
__global__ __launch_bounds__(256) void k_final2(const float* __restrict__ feat,
                                                const u16* __restrict__ WfragR,
                                                const float* __restrict__ b_res,
                                                const float* __restrict__ alpha,
                                                const float* __restrict__ Wx,
                                                const u16* __restrict__ agg,
                                                float* __restrict__ outp) {
    const int ty = blockIdx.y;
    const int rA = ty ? 0 : 1, rB = ty ? 2 : 3;
    const int t = threadIdx.x, lane = t & 63;
    const int li = lane & 15, g = lane >> 4;
    const int wid = blockIdx.x * 4 + (t >> 6);
    const int nw = gridDim.x * 4;
    const float ga = 1.f / (1.f + __expf(-alpha[ty]));
    const float gb = 1.f - ga;
    f32x4 zz = {0.f, 0.f, 0.f, 0.f};

    bf16x8 afr[16];
    #pragma unroll
    for (int ct = 0; ct < 16; ++ct) {
        U8 u;
        u.u = *(const uint4*)(WfragR + (((size_t)ty * 16 + ct) * 64 + lane) * 8);
        afr[ct] = u.v;
    }
    const float* FA = feat + (size_t)rA * NN * INF_;
    const float* FB = feat + (size_t)rB * NN * INF_;
    const u16* AG1 = agg + (size_t)rA * NN * HD;
    const u16* AG2 = agg + (size_t)rB * NN * HD;

    for (int tile = wid; tile < NN / 16; tile += nw) {
        const int node = tile * 16 + li;
        const float* fp1 = FA + (size_t)node * 32 + g * 8;
        const float* fp2 = FB + (size_t)node * 32 + g * 8;
        float4 x0 = *(const float4*)fp1, x1 = *(const float4*)(fp1 + 4);
        float4 y0 = *(const float4*)fp2, y1 = *(const float4*)(fp2 + 4);
        U8 b1, b2;
        b1.u.x = cvtpk(x0.x, x0.y); b1.u.y = cvtpk(x0.z, x0.w);
        b1.u.z = cvtpk(x1.x, x1.y); b1.u.w = cvtpk(x1.z, x1.w);
        b2.u.x = cvtpk(y0.x, y0.y); b2.u.y = cvtpk(y0.z, y0.w);
        b2.u.z = cvtpk(y1.x, y1.y); b2.u.w = cvtpk(y1.z, y1.w);

        float at1[8], at2[8];
        #pragma unroll
        for (int h = 0; h < 8; ++h) { at1[h] = 0.f; at2[h] = 0.f; }

        #pragma unroll
        for (int ct = 0; ct < 16; ++ct) {
            f32x4 r1 = __builtin_amdgcn_mfma_f32_16x16x32_bf16(afr[ct], b1.v, zz, 0, 0, 0);
            f32x4 r2 = __builtin_amdgcn_mfma_f32_16x16x32_bf16(afr[ct], b2.v, zz, 0, 0, 0);
            uint2 g1 = *(const uint2*)(AG1 + (size_t)node * HD + ct * 16 + g * 4);
            uint2 g2 = *(const uint2*)(AG2 + (size_t)node * HD + ct * 16 + g * 4);
            float4 bv = *(const float4*)(b_res + ty * 256 + ct * 16 + g * 4);
            float4 wv = *(const float4*)(Wx + ty * 256 + ct * 16 + g * 4);
            float o10 = fmaxf(blo(g1.x), 0.f) * ga + (r1[0] + bv.x) * gb;
            float o11 = fmaxf(bhi(g1.x), 0.f) * ga + (r1[1] + bv.y) * gb;
            float o12 = fmaxf(blo(g1.y), 0.f) * ga + (r1[2] + bv.z) * gb;
            float o13 = fmaxf(bhi(g1.y), 0.f) * ga + (r1[3] + bv.w) * gb;
            float o20 = fmaxf(blo(g2.x), 0.f) * ga + (r2[0] + bv.x) * gb;
            float o21 = fmaxf(bhi(g2.x), 0.f) * ga + (r2[1] + bv.y) * gb;
            float o22 = fmaxf(blo(g2.y), 0.f) * ga + (r2[2] + bv.z) * gb;
            float o23 = fmaxf(bhi(g2.y), 0.f) * ga + (r2[3] + bv.w) * gb;
            at1[ct >> 1] += o10 * wv.x + o11 * wv.y + o12 * wv.z + o13 * wv.w;
            at2[ct >> 1] += o20 * wv.x + o21 * wv.y + o22 * wv.z + o23 * wv.w;
        }
        #pragma unroll
        for (int h = 0; h < 8; ++h) {
            at1[h] += __shfl_xor(at1[h], 16, 64);
            at1[h] += __shfl_xor(at1[h], 32, 64);
            at2[h] += __shfl_xor(at2[h], 16, 64);
            at2[h] += __shfl_xor(at2[h], 32, 64);
        }
        float w1[8], w2[8];
        #pragma unroll
        for (int h = 0; h < 8; ++h) {
            float a1l = leaky(at1[h]), a2l = leaky(at2[h]);
            float mx = fmaxf(a1l, a2l);
            float e1 = __expf(a1l - mx), e2 = __expf(a2l - mx);
            float inv = 1.f / (e1 + e2);
            w1[h] = e1 * inv;
            w2[h] = e2 * inv;
        }
        float* op = outp + ((size_t)ty * NN + node) * HD;
        #pragma unroll
        for (int ct = 0; ct < 16; ++ct) {
            f32x4 r1 = __builtin_amdgcn_mfma_f32_16x16x32_bf16(afr[ct], b1.v, zz, 0, 0, 0);
            f32x4 r2 = __builtin_amdgcn_mfma_f32_16x16x32_bf16(afr[ct], b2.v, zz, 0, 0, 0);
            uint2 g1 = *(const uint2*)(AG1 + (size_t)node * HD + ct * 16 + g * 4);
            uint2 g2 = *(const uint2*)(AG2 + (size_t)node * HD + ct * 16 + g * 4);
            float4 bv = *(const float4*)(b_res + ty * 256 + ct * 16 + g * 4);
            float wa = w1[ct >> 1], wb = w2[ct >> 1];
            float4 o;
            o.x = (fmaxf(blo(g1.x), 0.f) * ga + (r1[0] + bv.x) * gb) * wa +
                  (fmaxf(blo(g2.x), 0.f) * ga + (r2[0] + bv.x) * gb) * wb;
            o.y = (fmaxf(bhi(g1.x), 0.f) * ga + (r1[1] + bv.y) * gb) * wa +
                  (fmaxf(bhi(g2.x), 0.f) * ga + (r2[1] + bv.y) * gb) * wb;
            o.z = (fmaxf(blo(g1.y), 0.f) * ga + (r1[2] + bv.z) * gb) * wa +
                  (fmaxf(blo(g2.y), 0.f) * ga + (r2[2] + bv.z) * gb) * wb;
            o.w = (fmaxf(bhi(g1.y), 0.f) * ga + (r1[3] + bv.w) * gb) * wa +
                  (fmaxf(bhi(g2.y), 0.f) * ga + (r2[3] + bv.w) * gb) * wb;
            *(float4*)(op + ct * 16 + g * 4) = o;
        }
    }
}

extern "C" void kernel_launch(void* const* d_in, const int* in_sizes, int n_in,
                              void* d_out, int out_size, void* d_ws, size_t ws_size,
                              hipStream_t stream) {
    const float* feat    = (const float*)d_in[0];
    const float* rel_emb = (const float*)d_in[1];
    const float* W_node  = (const float*)d_in[2];
    const float* W_rel   = (const float*)d_in[3];
    const float* W_prop  = (const float*)d_in[4];
    const float* b_prop  = (const float*)d_in[5];
    const float* W_res   = (const float*)d_in[6];
    const float* b_res   = (const float*)d_in[7];
    const float* alpha   = (const float*)d_in[8];
    const float* Wx      = (const float*)d_in[9];
    const int*   src     = (const int*)d_in[10];
    const int*   dst     = (const int*)d_in[11];
    float* out = (float*)d_out;

    // ws: ra | e_src | e_dst | P | Wfrag | deg | offsets | cursor | incl | bsum | bofs | esorted | agg
    char* ws = (char*)d_ws;
    float* ra      = (float*)ws;                            // 8 KB
    float* e_src   = (float*)(ws + 8192);                   // 12.8 MB
    float* e_dst   = e_src + (size_t)4 * NN * H;            // 12.8 MB
    u16*   P       = (u16*)(e_dst + (size_t)4 * NN * H);    // 204.8 MB
    u16*   Wfrag   = (u16*)((char*)P + (size_t)4 * NN * HD * 2);  // 102.4 KB
    u32*   deg     = (u32*)((char*)Wfrag + 102400);
    u32*   offsets = deg + L_;
    u32*   cursor  = offsets + L_;
    u32*   incl    = cursor + L_;
    u32*   bsum    = incl + L_;
    u32*   bofs    = bsum + 2048;
    int*   esorted = (int*)(bofs + 2048);                   // 8 MB
    u16*   agg     = (u16*)(esorted + (size_t)4 * EE);      // 204.8 MB (bf16, [4][NN][256])

    hipMemsetAsync(deg, 0, (size_t)L_ * 4, stream);

    k_prep<<<12, 256, 0, stream>>>(rel_emb, W_rel, W_prop, b_prop, ra, out + (size_t)2 * NN * HD);
    k_wfrag<<<200, 256, 0, stream>>>(W_node, W_res, ra, Wfrag);

    int eb = (4 * EE + 255) / 256;
    k_count<<<eb, 256, 0, stream>>>(dst, deg);
    k_scan1<<<NB_, 256, 0, stream>>>(deg, incl, bsum);
    k_scan2<<<1, 256, 0, stream>>>(bsum, bofs);
    k_scan3<<<NB_, 256, 0, stream>>>(deg, incl, bofs, offsets, cursor);
    k_fill<<<eb, 256, 0, stream>>>(src, dst, cursor, esorted);

    k_proj_mfma<<<dim3(512, 4), 256, 0, stream>>>(feat, Wfrag, e_src, e_dst, P);

    k_node_msg<<<dim3(NN / 4, 4), 256, 0, stream>>>(offsets, deg, esorted, e_src, e_dst, P, agg);

    k_final2<<<dim3(391, 2), 256, 0, stream>>>(feat, Wfrag + 4 * 17 * 512, b_res, alpha, Wx, agg, out);
}

// Round 8
// 664.516 us; speedup vs baseline: 13.2923x; 1.2611x over previous
//
#include <hip/hip_runtime.h>
#include <hip/hip_bf16.h>

#define NN 100000
#define EE 500000
#define H 8
#define D 32
#define INF_ 32
#define HD 256
#define SLOPE 0.2f
#define L_ (4 * NN)
#define NB_ ((L_ + 255) / 256)

typedef unsigned short u16;
typedef unsigned int u32;
typedef short bf16x8 __attribute__((ext_vector_type(8)));
typedef float f32x4 __attribute__((ext_vector_type(4)));

union U8 { uint4 u; bf16x8 v; };

__device__ __forceinline__ float leaky(float x) { return x >= 0.f ? x : SLOPE * x; }
__device__ __forceinline__ u16 bf16r(float x) {
    u32 u = __float_as_uint(x);
    u += 0x7fffu + ((u >> 16) & 1u);
    return (u16)(u >> 16);
}
__device__ __forceinline__ float bf16f(u16 v) { return __uint_as_float((u32)v << 16); }
__device__ __forceinline__ u32 cvtpk(float lo, float hi) {
    u32 r;
    asm("v_cvt_pk_bf16_f32 %0, %1, %2" : "=v"(r) : "v"(lo), "v"(hi));
    return r;
}

// ---------------- tiny prep: ra[4][512] and rel_out[4][256] ----------------
__global__ void k_prep(const float* __restrict__ rel_emb, const float* __restrict__ W_rel,
                       const float* __restrict__ W_prop, const float* __restrict__ b_prop,
                       float* __restrict__ ra, float* __restrict__ rel_out) {
    int idx = blockIdx.x * blockDim.x + threadIdx.x;
    if (idx < 4 * 512) {
        int r = idx >> 9, o = idx & 511;
        float s = 0.f;
        #pragma unroll
        for (int i = 0; i < INF_; ++i) s += rel_emb[r * INF_ + i] * W_rel[(r * INF_ + i) * 512 + o];
        ra[idx] = s;
    } else if (idx < 4 * 512 + 4 * 256) {
        int j = idx - 2048;
        int r = j >> 8;
        float s = b_prop[j];
        #pragma unroll
        for (int i = 0; i < INF_; ++i) s += rel_emb[r * INF_ + i] * W_prop[(r * INF_ + i) * 256 + (j & 255)];
        rel_out[j] = s;
    }
}

// ---------------- build MFMA A-operand fragments (bf16) ----------------
// layout (u16 units, frag stride 512 = 64 lanes * 8):
//   [0*512 ..  4*512): score frag per rel q: i<8 -> Wes_q[k][i], i>=8 -> Wed[k][i-8]
//   [4*512 .. 36*512): Wnode frag: ty*16+ct: A[i][k] = W_node[ty][k][ct*16+i]
//   [36*512.. 68*512): Wres  frag: ty*16+ct: A[i][k] = W_res [ty][k][ct*16+i]
__global__ void k_wfrag(const float* __restrict__ W_node, const float* __restrict__ W_res,
                        const float* __restrict__ ra, u16* __restrict__ Wfrag) {
    int idx = blockIdx.x * 256 + threadIdx.x;
    if (idx >= 68 * 512) return;
    int lb = idx & 511;
    int l = lb >> 3, b = lb & 7;
    int k = (l >> 4) * 8 + b, i = l & 15;
    float v;
    if (idx < 4 * 512) {
        int q = idx >> 9;
        int rq = q ^ 1;
        const float* W = W_node + (size_t)(q & 1) * 32 * 256;
        int h = i & 7;
        const float* rr = (i < 8) ? (ra + q * 512 + h * 64 + 32) : (ra + rq * 512 + h * 64);
        float s = 0.f;
        #pragma unroll
        for (int j = 0; j < 32; ++j) s += W[k * 256 + h * 32 + j] * rr[j];
        v = s;
    } else if (idx < 36 * 512) {
        int j = idx - 4 * 512;
        int ty = j >> 13;               // 16*512 per type
        int ct = (j & 8191) >> 9;
        v = W_node[(size_t)ty * 32 * 256 + k * 256 + ct * 16 + i];
    } else {
        int j = idx - 36 * 512;
        int ty = j >> 13;
        int ct = (j & 8191) >> 9;
        v = W_res[(size_t)ty * 32 * 256 + k * 256 + ct * 16 + i];
    }
    Wfrag[idx] = bf16r(v);
}

// ---------------- scores + bf16 feat copy (1 MFMA per 16 nodes) ----------------
__global__ __launch_bounds__(256) void k_score(const float* __restrict__ feat,
                                               const u16* __restrict__ Wfrag,
                                               float* __restrict__ e_src,
                                               float* __restrict__ e_dst,
                                               u16* __restrict__ featb) {
    const int q = blockIdx.y, rq = q ^ 1;
    const int t = threadIdx.x, lane = t & 63;
    const int li = lane & 15, g = lane >> 4;
    const int wid = blockIdx.x * 4 + (t >> 6);
    const int nw = gridDim.x * 4;
    f32x4 zz = {0.f, 0.f, 0.f, 0.f};
    U8 a;
    a.u = *(const uint4*)(Wfrag + ((size_t)q * 64 + lane) * 8);
    const float* F = feat + (size_t)rq * NN * INF_;
    u16* Fb = featb + (size_t)rq * NN * INF_;
    for (int tile = wid; tile < NN / 16; tile += nw) {
        const int node = tile * 16 + li;
        const float* fp = F + (size_t)node * 32 + g * 8;
        float4 f0 = *(const float4*)fp;
        float4 f1 = *(const float4*)(fp + 4);
        U8 b;
        b.u.x = cvtpk(f0.x, f0.y); b.u.y = cvtpk(f0.z, f0.w);
        b.u.z = cvtpk(f1.x, f1.y); b.u.w = cvtpk(f1.z, f1.w);
        *(uint4*)(Fb + (size_t)node * 32 + g * 8) = b.u;
        f32x4 sc = __builtin_amdgcn_mfma_f32_16x16x32_bf16(a.v, b.v, zz, 0, 0, 0);
        float* sp = (g < 2) ? (e_src + ((size_t)q * NN + node) * 8 + (g & 1) * 4)
                            : (e_dst + ((size_t)rq * NN + node) * 8 + (g & 1) * 4);
        *(float4*)sp = make_float4(sc[0], sc[1], sc[2], sc[3]);
    }
}

// ---------------- CSR build ----------------
__global__ void k_count(const int* __restrict__ dst, u32* __restrict__ deg) {
    int idx = blockIdx.x * blockDim.x + threadIdx.x;
    if (idx >= 4 * EE) return;
    int r = idx / EE;
    atomicAdd(&deg[r * NN + dst[idx]], 1u);
}

__global__ void k_scan1(const u32* __restrict__ deg, u32* __restrict__ incl, u32* __restrict__ bsum) {
    __shared__ u32 sm[256];
    const int t = threadIdx.x;
    int i = blockIdx.x * 256 + t;
    u32 v = (i < L_) ? deg[i] : 0u;
    sm[t] = v;
    __syncthreads();
    for (int ofs = 1; ofs < 256; ofs <<= 1) {
        u32 x = (t >= ofs) ? sm[t - ofs] : 0u;
        __syncthreads();
        sm[t] += x;
        __syncthreads();
    }
    if (i < L_) incl[i] = sm[t];
    if (t == 255) bsum[blockIdx.x] = sm[255];
}

__global__ void k_scan2(const u32* __restrict__ bsum, u32* __restrict__ bofs) {
    __shared__ u32 sm[256];
    __shared__ u32 runS;
    const int t = threadIdx.x;
    if (t == 0) runS = 0u;
    __syncthreads();
    for (int c = 0; c < NB_; c += 256) {
        u32 v = (c + t < NB_) ? bsum[c + t] : 0u;
        sm[t] = v;
        __syncthreads();
        for (int ofs = 1; ofs < 256; ofs <<= 1) {
            u32 x = (t >= ofs) ? sm[t - ofs] : 0u;
            __syncthreads();
            sm[t] += x;
            __syncthreads();
        }
        u32 excl = sm[t] - v;
        if (c + t < NB_) bofs[c + t] = runS + excl;
        __syncthreads();
        if (t == 255) runS += sm[255];
        __syncthreads();
    }
}

__global__ void k_scan3(const u32* __restrict__ deg, const u32* __restrict__ incl,
                        const u32* __restrict__ bofs, u32* __restrict__ offsets,
                        u32* __restrict__ cursor) {
    int i = blockIdx.x * 256 + threadIdx.x;
    if (i >= L_) return;
    u32 excl = incl[i] - deg[i] + bofs[i >> 8];
    offsets[i] = excl;
    cursor[i] = excl;
}

__global__ void k_fill(const int* __restrict__ src, const int* __restrict__ dst,
                       u32* __restrict__ cursor, int* __restrict__ esorted) {
    int idx = blockIdx.x * blockDim.x + threadIdx.x;
    if (idx >= 4 * EE) return;
    int r = idx / EE;
    u32 pos = atomicAdd(&cursor[r * NN + dst[idx]], 1u);
    esorted[pos] = src[idx];
}

// ---------------- per-dst-node softmax-weighted RAW-feature aggregation ----------------
// linearity: msg = (sum_k a_k * feat[s_k]) @ W  -> gather 64B/edge instead of 512B.
// lane owns (head h = lane>>3, features fq*4..fq*4+3, fq = lane&7).
// aggfeat[r][n][h*32 + fq*4 + j]  (== lane*4+j)
__global__ __launch_bounds__(256) void k_node_msg(const u32* __restrict__ offsets,
                                                  const u32* __restrict__ deg,
                                                  const int* __restrict__ esorted,
                                                  const float* __restrict__ e_src,
                                                  const float* __restrict__ e_dst,
                                                  const u16* __restrict__ featb,
                                                  u16* __restrict__ aggf) {
    const int r = blockIdx.y;
    const int t = threadIdx.x, lane = t & 63;
    const int n = blockIdx.x * 4 + (t >> 6);
    const int h = lane >> 3, fq = lane & 7;
    const int i = r * NN + n;
    const u32 off = offsets[i], dg = deg[i];
    u16* ap = aggf + ((size_t)r * NN + n) * HD + lane * 4;
    if (dg == 0) {
        uint2 z2 = {0u, 0u};
        *(uint2*)ap = z2;
        return;
    }
    const float ed = e_dst[(size_t)i * 8 + h];
    const float* esr = e_src + (size_t)r * NN * 8;
    const u16* Fb = featb + (size_t)(r ^ 1) * NN * INF_;
    float z = 0.f, a0 = 0.f, a1 = 0.f, a2 = 0.f, a3 = 0.f;
    const int sd = esorted[off];
    for (u32 k = 0; k < dg; k += 8) {
        int s[8];
        s[0] = esorted[off + k];
        #pragma unroll
        for (int j = 1; j < 8; ++j) s[j] = (k + j < dg) ? esorted[off + k + j] : sd;
        float e[8];
        ushort4 f[8];
        #pragma unroll
        for (int j = 0; j < 8; ++j) {
            e[j] = esr[(size_t)s[j] * 8 + h];
            f[j] = *(const ushort4*)(Fb + (size_t)s[j] * INF_ + fq * 4);
        }
        float w[8];
        w[0] = __expf(leaky(e[0] + ed));
        #pragma unroll
        for (int j = 1; j < 8; ++j)
            w[j] = (k + j < dg) ? __expf(leaky(e[j] + ed)) : 0.f;
        #pragma unroll
        for (int j = 0; j < 8; ++j) {
            z += w[j];
            a0 = fmaf(bf16f(f[j].x), w[j], a0);
            a1 = fmaf(bf16f(f[j].y), w[j], a1);
            a2 = fmaf(bf16f(f[j].z), w[j], a2);
            a3 = fmaf(bf16f(f[j].w), w[j], a3);
        }
    }
    float inv = 1.f / z;
    uint2 st;
    st.x = cvtpk(a0 * inv, a1 * inv);
    st.y = cvtpk(a2 * inv, a3 * inv);
    *(uint2*)ap = st;
}

// ---------------- finalize: project aggfeat per head, residual, gate, crossing ----------------
// msg projection W = W_node[st] with st = 1-ty (relations targeting type ty have src type 1-ty);
// residual W = W_res[dt] = W_res[ty].
__global__ __launch_bounds__(256) void k_final3(const u16* __restrict__ featb,
                                                const u16* __restrict__ Wfrag,
                                                const float* __restrict__ b_res,
                                                const float* __restrict__ alpha,
                                                const float* __restrict__ Wx,
                                                const u16* __restrict__ aggf,
                                                float* __restrict__ outp) {
    const int ty = blockIdx.y;
    const int rA = ty ? 0 : 1, rB = ty ? 2 : 3;
    const int t = threadIdx.x, lane = t & 63;
    const int li = lane & 15, g = lane >> 4;
    const int wid = blockIdx.x * 4 + (t >> 6);
    const int nw = gridDim.x * 4;
    const float ga = 1.f / (1.f + __expf(-alpha[ty]));
    const float gb = 1.f - ga;
    f32x4 zz = {0.f, 0.f, 0.f, 0.f};
    const u16* WnF = Wfrag + (size_t)(4 + (1 - ty) * 16) * 512;   // W_node[st=1-ty]
    const u16* WrF = Wfrag + (size_t)(36 + ty * 16) * 512;        // W_res[dt=ty]
    const u16* FbA = featb + (size_t)rA * NN * INF_;
    const u16* FbB = featb + (size_t)rB * NN * INF_;
    const u16* AgA = aggf + (size_t)rA * NN * HD;
    const u16* AgB = aggf + (size_t)rB * NN * HD;

    for (int tile = wid; tile < NN / 16; tile += nw) {
        const int node = tile * 16 + li;
        U8 fA, fB;
        fA.u = *(const uint4*)(FbA + (size_t)node * 32 + g * 8);
        fB.u = *(const uint4*)(FbB + (size_t)node * 32 + g * 8);
        U8 agA[8], agB[8];
        #pragma unroll
        for (int h = 0; h < 8; ++h) {
            agA[h].u = *(const uint4*)(AgA + (size_t)node * HD + h * 32 + g * 8);
            agB[h].u = *(const uint4*)(AgB + (size_t)node * HD + h * 32 + g * 8);
        }
        float at1[8], at2[8];
        #pragma unroll
        for (int h = 0; h < 8; ++h) { at1[h] = 0.f; at2[h] = 0.f; }

        #pragma unroll
        for (int ct = 0; ct < 16; ++ct) {
            U8 wn, wr;
            wn.u = *(const uint4*)(WnF + ((size_t)ct * 64 + lane) * 8);
            wr.u = *(const uint4*)(WrF + ((size_t)ct * 64 + lane) * 8);
            f32x4 m1 = __builtin_amdgcn_mfma_f32_16x16x32_bf16(wn.v, agA[ct >> 1].v, zz, 0, 0, 0);
            f32x4 m2 = __builtin_amdgcn_mfma_f32_16x16x32_bf16(wn.v, agB[ct >> 1].v, zz, 0, 0, 0);
            f32x4 r1 = __builtin_amdgcn_mfma_f32_16x16x32_bf16(wr.v, fA.v, zz, 0, 0, 0);
            f32x4 r2 = __builtin_amdgcn_mfma_f32_16x16x32_bf16(wr.v, fB.v, zz, 0, 0, 0);
            float4 bv = *(const float4*)(b_res + ty * 256 + ct * 16 + g * 4);
            float4 wv = *(const float4*)(Wx + ty * 256 + ct * 16 + g * 4);
            float s1 = 0.f, s2 = 0.f;
            #pragma unroll
            for (int j = 0; j < 4; ++j) {
                float bj = (&bv.x)[j], wj = (&wv.x)[j];
                float o1 = fmaxf(m1[j], 0.f) * ga + (r1[j] + bj) * gb;
                float o2 = fmaxf(m2[j], 0.f) * ga + (r2[j] + bj) * gb;
                s1 += o1 * wj;
                s2 += o2 * wj;
            }
            at1[ct >> 1] += s1;
            at2[ct >> 1] += s2;
        }
        #pragma unroll
        for (int h = 0; h < 8; ++h) {
            at1[h] += __shfl_xor(at1[h], 16, 64);
            at1[h] += __shfl_xor(at1[h], 32, 64);
            at2[h] += __shfl_xor(at2[h], 16, 64);
            at2[h] += __shfl_xor(at2[h], 32, 64);
        }
        float w1[8], w2[8];
        #pragma unroll
        for (int h = 0; h < 8; ++h) {
            float a1l = leaky(at1[h]), a2l = leaky(at2[h]);
            float mx = fmaxf(a1l, a2l);
            float e1 = __expf(a1l - mx), e2 = __expf(a2l - mx);
            float inv = 1.f / (e1 + e2);
            w1[h] = e1 * inv;
            w2[h] = e2 * inv;
        }
        float* op = outp + ((size_t)ty * NN + node) * HD;
        #pragma unroll
        for (int ct = 0; ct < 16; ++ct) {
            U8 wn, wr;
            wn.u = *(const uint4*)(WnF + ((size_t)ct * 64 + lane) * 8);
            wr.u = *(const uint4*)(WrF + ((size_t)ct * 64 + lane) * 8);
            f32x4 m1 = __builtin_amdgcn_mfma_f32_16x16x32_bf16(wn.v, agA[ct >> 1].v, zz, 0, 0, 0);
            f32x4 m2 = __builtin_amdgcn_mfma_f32_16x16x32_bf16(wn.v, agB[ct >> 1].v, zz, 0, 0, 0);
            f32x4 r1 = __builtin_amdgcn_mfma_f32_16x16x32_bf16(wr.v, fA.v, zz, 0, 0, 0);
            f32x4 r2 = __builtin_amdgcn_mfma_f32_16x16x32_bf16(wr.v, fB.v, zz, 0, 0, 0);
            float4 bv = *(const float4*)(b_res + ty * 256 + ct * 16 + g * 4);
            float wa = w1[ct >> 1], wb = w2[ct >> 1];
            float4 o;
            #pragma unroll
            for (int j = 0; j < 4; ++j) {
                float bj = (&bv.x)[j];
                float o1 = fmaxf(m1[j], 0.f) * ga + (r1[j] + bj) * gb;
                float o2 = fmaxf(m2[j], 0.f) * ga + (r2[j] + bj) * gb;
                (&o.x)[j] = o1 * wa + o2 * wb;
            }
            *(float4*)(op + ct * 16 + g * 4) = o;
        }
    }
}

extern "C" void kernel_launch(void* const* d_in, const int* in_sizes, int n_in,
                              void* d_out, int out_size, void* d_ws, size_t ws_size,
                              hipStream_t stream) {
    const float* feat    = (const float*)d_in[0];
    const float* rel_emb = (const float*)d_in[1];
    const float* W_node  = (const float*)d_in[2];
    const float* W_rel   = (const float*)d_in[3];
    const float* W_prop  = (const float*)d_in[4];
    const float* b_prop  = (const float*)d_in[5];
    const float* W_res   = (const float*)d_in[6];
    const float* b_res   = (const float*)d_in[7];
    const float* alpha   = (const float*)d_in[8];
    const float* Wx      = (const float*)d_in[9];
    const int*   src     = (const int*)d_in[10];
    const int*   dst     = (const int*)d_in[11];
    float* out = (float*)d_out;

    // ws: ra | e_src | e_dst | featb | Wfrag | deg | offsets | cursor | incl | bsum | bofs | esorted | aggf
    char* ws = (char*)d_ws;
    float* ra      = (float*)ws;                            // 8 KB
    float* e_src   = (float*)(ws + 8192);                   // 12.8 MB
    float* e_dst   = e_src + (size_t)4 * NN * H;            // 12.8 MB
    u16*   featb   = (u16*)(e_dst + (size_t)4 * NN * H);    // 25.6 MB
    u16*   Wfrag   = featb + (size_t)4 * NN * INF_;         // 68 KB
    u32*   deg     = (u32*)(Wfrag + 68 * 512);
    u32*   offsets = deg + L_;
    u32*   cursor  = offsets + L_;
    u32*   incl    = cursor + L_;
    u32*   bsum    = incl + L_;
    u32*   bofs    = bsum + 2048;
    int*   esorted = (int*)(bofs + 2048);                   // 8 MB
    u16*   aggf    = (u16*)(esorted + (size_t)4 * EE);      // 204.8 MB (bf16, [4][NN][256])

    hipMemsetAsync(deg, 0, (size_t)L_ * 4, stream);

    k_prep<<<12, 256, 0, stream>>>(rel_emb, W_rel, W_prop, b_prop, ra, out + (size_t)2 * NN * HD);
    k_wfrag<<<136, 256, 0, stream>>>(W_node, W_res, ra, Wfrag);

    int eb = (4 * EE + 255) / 256;
    k_count<<<eb, 256, 0, stream>>>(dst, deg);
    k_scan1<<<NB_, 256, 0, stream>>>(deg, incl, bsum);
    k_scan2<<<1, 256, 0, stream>>>(bsum, bofs);
    k_scan3<<<NB_, 256, 0, stream>>>(deg, incl, bofs, offsets, cursor);
    k_fill<<<eb, 256, 0, stream>>>(src, dst, cursor, esorted);

    k_score<<<dim3(512, 4), 256, 0, stream>>>(feat, Wfrag, e_src, e_dst, featb);

    k_node_msg<<<dim3(NN / 4, 4), 256, 0, stream>>>(offsets, deg, esorted, e_src, e_dst, featb, aggf);

    k_final3<<<dim3(391, 2), 256, 0, stream>>>(featb, Wfrag, b_res, alpha, Wx, aggf, out);
}